// Round 1
// baseline (1616.876 us; speedup 1.0000x reference)
//
#include <hip/hip_runtime.h>

#define H 64
#define NCLS 2

// ---------------- CSR build ----------------

__global__ void count_deg(const int* __restrict__ dst, int* __restrict__ deg, int e) {
    int i = blockIdx.x * 256 + threadIdx.x;
    if (i < e) atomicAdd(&deg[dst[i]], 1);
}

// block-level exclusive scan: 256 threads x 4 elems = 1024 per block
__global__ void scan1(const int* __restrict__ in, int* __restrict__ out,
                      int* __restrict__ bsum, int n) {
    __shared__ int s[256];
    int tid = threadIdx.x;
    int base = blockIdx.x * 1024 + tid * 4;
    int v0 = (base + 0 < n) ? in[base + 0] : 0;
    int v1 = (base + 1 < n) ? in[base + 1] : 0;
    int v2 = (base + 2 < n) ? in[base + 2] : 0;
    int v3 = (base + 3 < n) ? in[base + 3] : 0;
    int lsum = v0 + v1 + v2 + v3;
    s[tid] = lsum;
    __syncthreads();
    for (int off = 1; off < 256; off <<= 1) {
        int t = (tid >= off) ? s[tid - off] : 0;
        __syncthreads();
        s[tid] += t;
        __syncthreads();
    }
    int excl = s[tid] - lsum;
    if (base + 0 < n) out[base + 0] = excl;
    if (base + 1 < n) out[base + 1] = excl + v0;
    if (base + 2 < n) out[base + 2] = excl + v0 + v1;
    if (base + 3 < n) out[base + 3] = excl + v0 + v1 + v2;
    if (tid == 255) bsum[blockIdx.x] = s[255];
}

__global__ void scan2(const int* __restrict__ bsum, int* __restrict__ boff, int nb) {
    __shared__ int s[256];
    int tid = threadIdx.x;
    int v = (tid < nb) ? bsum[tid] : 0;
    s[tid] = v;
    __syncthreads();
    for (int off = 1; off < 256; off <<= 1) {
        int t = (tid >= off) ? s[tid - off] : 0;
        __syncthreads();
        s[tid] += t;
        __syncthreads();
    }
    if (tid < nb) boff[tid] = s[tid] - v;
}

__global__ void scan3(int* __restrict__ rowptr, const int* __restrict__ boff,
                      int n, int total) {
    int i = blockIdx.x * 256 + threadIdx.x;
    if (i < n) rowptr[i] += boff[i >> 10];
    else if (i == n) rowptr[n] = total;
}

__global__ void fill_csr(const int* __restrict__ src, const int* __restrict__ dst,
                         const int* __restrict__ rowptr, int* __restrict__ cursor,
                         int* __restrict__ col, int e) {
    int i = blockIdx.x * 256 + threadIdx.x;
    if (i < e) {
        int d = dst[i];
        int p = atomicAdd(&cursor[d], 1);
        col[rowptr[d] + p] = src[i];
    }
}

// ---------------- dense transforms: TL = X@Wl ; TR = X@Wr + bias ----------------

template <int K, int ROWS>
__launch_bounds__(256)
__global__ void transform2(const float* __restrict__ X,
                           const float* __restrict__ Wl,
                           const float* __restrict__ Wr,
                           const float* __restrict__ bias,
                           float* __restrict__ TL, float* __restrict__ TR, int n) {
    __shared__ float sW[K * 64];
    const int tid = threadIdx.x;
    const int col = tid & 63;
    const int wv = tid >> 6;
    const int rowBase = blockIdx.x * ROWS;

    for (int i = tid; i < K * 64; i += 256) sW[i] = Wl[i];
    __syncthreads();
    for (int r = rowBase + wv; r < rowBase + ROWS; r += 4) {
        if (r >= n) break;
        const float* xr = X + (size_t)r * K;
        float acc = 0.f;
#pragma unroll 8
        for (int k = 0; k < K; ++k) acc = fmaf(xr[k], sW[k * 64 + col], acc);
        TL[(size_t)r * 64 + col] = acc;
    }
    __syncthreads();
    for (int i = tid; i < K * 64; i += 256) sW[i] = Wr[i];
    __syncthreads();
    float b = bias[col];
    for (int r = rowBase + wv; r < rowBase + ROWS; r += 4) {
        if (r >= n) break;
        const float* xr = X + (size_t)r * K;
        float acc = b;
#pragma unroll 8
        for (int k = 0; k < K; ++k) acc = fmaf(xr[k], sW[k * 64 + col], acc);
        TR[(size_t)r * 64 + col] = acc;
    }
}

// ---------------- CSR aggregate + finalize: OUT = relu(agg(TL)/deg + TR) ----------------

__launch_bounds__(256)
__global__ void sage_agg(const float* __restrict__ TL, const float* __restrict__ TR,
                         const int* __restrict__ rowptr, const int* __restrict__ col,
                         float* __restrict__ OUT, int n) {
    int node = blockIdx.x * 4 + (threadIdx.x >> 6);
    int lane = threadIdx.x & 63;
    if (node >= n) return;
    int s = rowptr[node], e = rowptr[node + 1];
    float acc = 0.f;
    for (int i = s; i < e; i += 64) {
        int nchunk = min(64, e - i);
        int c = (i + lane < e) ? col[i + lane] : 0;
        int j = 0;
        for (; j + 4 <= nchunk; j += 4) {
            int i0 = __shfl(c, j, 64);
            int i1 = __shfl(c, j + 1, 64);
            int i2 = __shfl(c, j + 2, 64);
            int i3 = __shfl(c, j + 3, 64);
            float t0 = TL[(size_t)i0 * 64 + lane];
            float t1 = TL[(size_t)i1 * 64 + lane];
            float t2 = TL[(size_t)i2 * 64 + lane];
            float t3 = TL[(size_t)i3 * 64 + lane];
            acc += t0 + t1 + t2 + t3;
        }
        for (; j < nchunk; ++j) {
            int ix = __shfl(c, j, 64);
            acc += TL[(size_t)ix * 64 + lane];
        }
    }
    int deg = e - s;
    float v = acc / (float)max(deg, 1) + TR[(size_t)node * 64 + lane];
    OUT[(size_t)node * 64 + lane] = fmaxf(v, 0.f);
}

// ---------------- reparameterize + global mean pool (segmented, batch sorted) ----------------

__launch_bounds__(256)
__global__ void pool_z(const float* __restrict__ mean, const float* __restrict__ logv,
                       const float* __restrict__ eps, const int* __restrict__ batch,
                       float* __restrict__ gsum, int* __restrict__ gcnt, int n) {
    const int CHUNK = 512;
    int wv = threadIdx.x >> 6, lane = threadIdx.x & 63;
    int start = blockIdx.x * CHUNK + wv * (CHUNK / 4);
    int end = min(start + CHUNK / 4, n);
    if (start >= end) return;
    int gcur = batch[start];
    float acc = 0.f;
    int cnt = 0;
    for (int i = start; i < end; ++i) {
        int g = batch[i];
        if (g != gcur) {
            atomicAdd(&gsum[(size_t)gcur * 64 + lane], acc);
            if (lane == 0) atomicAdd(&gcnt[gcur], cnt);
            acc = 0.f;
            cnt = 0;
            gcur = g;
        }
        size_t o = (size_t)i * 64 + lane;
        float z = mean[o] + eps[o] * expf(0.5f * logv[o]);
        acc += z;
        cnt++;
    }
    atomicAdd(&gsum[(size_t)gcur * 64 + lane], acc);
    if (lane == 0) atomicAdd(&gcnt[gcur], cnt);
}

// ---------------- pooled -> fc1 -> relu -> fc2 -> log_softmax ----------------

__launch_bounds__(128)
__global__ void head(const float* __restrict__ gsum, const int* __restrict__ gcnt,
                     const float* __restrict__ fc1W, const float* __restrict__ fc1b,
                     const float* __restrict__ fc2W, const float* __restrict__ fc2b,
                     float* __restrict__ out) {
    __shared__ float pooled[64];
    __shared__ float h[128];
    __shared__ float lg[2];
    int g = blockIdx.x, tid = threadIdx.x;
    if (tid < 64) {
        int c = gcnt[g];
        pooled[tid] = gsum[(size_t)g * 64 + tid] / (float)max(c, 1);
    }
    __syncthreads();
    float acc = fc1b[tid];
    for (int k = 0; k < 64; ++k) acc = fmaf(pooled[k], fc1W[k * 128 + tid], acc);
    h[tid] = fmaxf(acc, 0.f);
    __syncthreads();
    if (tid < 2) {
        float a = fc2b[tid];
        for (int k = 0; k < 128; ++k) a = fmaf(h[k], fc2W[k * 2 + tid], a);
        lg[tid] = a;
    }
    __syncthreads();
    if (tid < 2) {
        float m = fmaxf(lg[0], lg[1]);
        float lse = m + logf(expf(lg[0] - m) + expf(lg[1] - m));
        out[(size_t)g * 2 + tid] = lg[tid] - lse;
    }
}

extern "C" void kernel_launch(void* const* d_in, const int* in_sizes, int n_in,
                              void* d_out, int out_size, void* d_ws, size_t ws_size,
                              hipStream_t stream) {
    const int N = in_sizes[19];       // batch [N]
    const int E = in_sizes[18] / 2;   // edge_index [2,E]
    const int G = (out_size - 2 * N * H) / NCLS;

    const float* x    = (const float*)d_in[0];
    const float* eps  = (const float*)d_in[1];
    const float* m0Wl = (const float*)d_in[2];
    const float* m0bl = (const float*)d_in[3];
    const float* m0Wr = (const float*)d_in[4];
    const float* mRWl = (const float*)d_in[5];
    const float* mRbl = (const float*)d_in[6];
    const float* mRWr = (const float*)d_in[7];
    const float* v0Wl = (const float*)d_in[8];
    const float* v0bl = (const float*)d_in[9];
    const float* v0Wr = (const float*)d_in[10];
    const float* vRWl = (const float*)d_in[11];
    const float* vRbl = (const float*)d_in[12];
    const float* vRWr = (const float*)d_in[13];
    const float* fc1W = (const float*)d_in[14];
    const float* fc1b = (const float*)d_in[15];
    const float* fc2W = (const float*)d_in[16];
    const float* fc2b = (const float*)d_in[17];
    const int* eidx   = (const int*)d_in[18];
    const int* batch  = (const int*)d_in[19];
    const int* srcI = eidx;
    const int* dstI = eidx + E;

    float* out_ls = (float*)d_out;
    float* out_mean = out_ls + (size_t)G * NCLS;
    float* out_lv = out_mean + (size_t)N * H;

    char* w = (char*)d_ws;
    auto alloc = [&](size_t bytes) {
        char* p = w;
        w += (bytes + 255) & ~(size_t)255;
        return p;
    };
    int* deg = (int*)alloc((size_t)N * 4);
    int* rowptr = (int*)alloc((size_t)(N + 1) * 4);
    int* cursor = (int*)alloc((size_t)N * 4);
    int* bsum = (int*)alloc(256 * 4);
    int* boff = (int*)alloc(256 * 4);
    int* col = (int*)alloc((size_t)E * 4);
    float* TL = (float*)alloc((size_t)N * H * 4);
    float* TR = (float*)alloc((size_t)N * H * 4);
    float* gsum = (float*)alloc((size_t)G * H * 4);
    int* gcnt = (int*)alloc((size_t)G * 4);
    (void)ws_size;
    (void)n_in;

    const int nbE = (E + 255) / 256;
    const int nbScan = (N + 1023) / 1024;

    // CSR build (reused by all 6 convs)
    hipMemsetAsync(deg, 0, (size_t)N * 4, stream);
    count_deg<<<nbE, 256, 0, stream>>>(dstI, deg, E);
    scan1<<<nbScan, 256, 0, stream>>>(deg, rowptr, bsum, N);
    scan2<<<1, 256, 0, stream>>>(bsum, boff, nbScan);
    scan3<<<(N + 256) / 256 + 1, 256, 0, stream>>>(rowptr, boff, N, E);
    hipMemsetAsync(cursor, 0, (size_t)N * 4, stream);
    fill_csr<<<nbE, 256, 0, stream>>>(srcI, dstI, rowptr, cursor, col, E);

    const int nbT128 = (N + 63) / 64;
    const int nbAgg = (N + 3) / 4;

    // layer 0 (in=128)
    transform2<128, 64><<<nbT128, 256, 0, stream>>>(x, m0Wl, m0Wr, m0bl, TL, TR, N);
    sage_agg<<<nbAgg, 256, 0, stream>>>(TL, TR, rowptr, col, out_mean, N);
    transform2<128, 64><<<nbT128, 256, 0, stream>>>(x, v0Wl, v0Wr, v0bl, TL, TR, N);
    sage_agg<<<nbAgg, 256, 0, stream>>>(TL, TR, rowptr, col, out_lv, N);

    // layers 1..2 (in=64)
    for (int i = 0; i < 2; ++i) {
        const float* wl = mRWl + (size_t)i * 64 * 64;
        const float* wr = mRWr + (size_t)i * 64 * 64;
        const float* bl = mRbl + (size_t)i * 64;
        transform2<64, 64><<<nbT128, 256, 0, stream>>>(out_mean, wl, wr, bl, TL, TR, N);
        sage_agg<<<nbAgg, 256, 0, stream>>>(TL, TR, rowptr, col, out_mean, N);
        const float* wlv = vRWl + (size_t)i * 64 * 64;
        const float* wrv = vRWr + (size_t)i * 64 * 64;
        const float* blv = vRbl + (size_t)i * 64;
        transform2<64, 64><<<nbT128, 256, 0, stream>>>(out_lv, wlv, wrv, blv, TL, TR, N);
        sage_agg<<<nbAgg, 256, 0, stream>>>(TL, TR, rowptr, col, out_lv, N);
    }

    // reparameterize + pool
    hipMemsetAsync(gsum, 0, (size_t)G * H * 4, stream);
    hipMemsetAsync(gcnt, 0, (size_t)G * 4, stream);
    pool_z<<<(N + 511) / 512, 256, 0, stream>>>(out_mean, out_lv, eps, batch, gsum, gcnt, N);

    // FC head + log_softmax
    head<<<G, 128, 0, stream>>>(gsum, gcnt, fc1W, fc1b, fc2W, fc2b, out_ls);
}

// Round 2
// 792.684 us; speedup vs baseline: 2.0397x; 2.0397x over previous
//
#include <hip/hip_runtime.h>

#define NH 64
#define NCLS 2

typedef short short8 __attribute__((ext_vector_type(8)));
typedef float f32x4 __attribute__((ext_vector_type(4)));

__device__ inline unsigned short f2bf(float x) {
    unsigned u = __float_as_uint(x);
    unsigned r = (u + 0x7FFFu + ((u >> 16) & 1u)) >> 16;
    return (unsigned short)r;
}
__device__ inline float bf2f(unsigned short h) { return __uint_as_float(((unsigned)h) << 16); }

// ---------------- CSR build ----------------

__global__ void count_deg(const int* __restrict__ dst, int* __restrict__ deg, int e) {
    int i = blockIdx.x * 256 + threadIdx.x;
    if (i < e) atomicAdd(&deg[dst[i]], 1);
}

__global__ void scan1(const int* __restrict__ in, int* __restrict__ out,
                      int* __restrict__ bsum, int n) {
    __shared__ int s[256];
    int tid = threadIdx.x;
    int base = blockIdx.x * 1024 + tid * 4;
    int v0 = (base + 0 < n) ? in[base + 0] : 0;
    int v1 = (base + 1 < n) ? in[base + 1] : 0;
    int v2 = (base + 2 < n) ? in[base + 2] : 0;
    int v3 = (base + 3 < n) ? in[base + 3] : 0;
    int lsum = v0 + v1 + v2 + v3;
    s[tid] = lsum;
    __syncthreads();
    for (int off = 1; off < 256; off <<= 1) {
        int t = (tid >= off) ? s[tid - off] : 0;
        __syncthreads();
        s[tid] += t;
        __syncthreads();
    }
    int excl = s[tid] - lsum;
    if (base + 0 < n) out[base + 0] = excl;
    if (base + 1 < n) out[base + 1] = excl + v0;
    if (base + 2 < n) out[base + 2] = excl + v0 + v1;
    if (base + 3 < n) out[base + 3] = excl + v0 + v1 + v2;
    if (tid == 255) bsum[blockIdx.x] = s[255];
}

__global__ void scan2(const int* __restrict__ bsum, int* __restrict__ boff, int nb) {
    __shared__ int s[256];
    int tid = threadIdx.x;
    int v = (tid < nb) ? bsum[tid] : 0;
    s[tid] = v;
    __syncthreads();
    for (int off = 1; off < 256; off <<= 1) {
        int t = (tid >= off) ? s[tid - off] : 0;
        __syncthreads();
        s[tid] += t;
        __syncthreads();
    }
    if (tid < nb) boff[tid] = s[tid] - v;
}

__global__ void scan3(int* __restrict__ rowptr, const int* __restrict__ boff,
                      int n, int total) {
    int i = blockIdx.x * 256 + threadIdx.x;
    if (i < n) rowptr[i] += boff[i >> 10];
    else if (i == n) rowptr[n] = total;
}

__global__ void fill_csr(const int* __restrict__ src, const int* __restrict__ dst,
                         const int* __restrict__ rowptr, int* __restrict__ cursor,
                         int* __restrict__ col, int e) {
    int i = blockIdx.x * 256 + threadIdx.x;
    if (i < e) {
        int d = dst[i];
        int p = atomicAdd(&cursor[d], 1);
        col[rowptr[d] + p] = src[i];
    }
}

// ---------------- weight prep: W^T in split bf16, [TL cols | TR cols] ----------------

__global__ void prep_w(const float* __restrict__ Wl, const float* __restrict__ Wr,
                       const float* __restrict__ bl, int K,
                       unsigned short* __restrict__ Wth, unsigned short* __restrict__ Wtl,
                       float* __restrict__ biasOut) {
    int tot = 128 * K;
    for (int idx = blockIdx.x * 256 + threadIdx.x; idx < tot; idx += gridDim.x * 256) {
        int c = idx / K, k = idx - c * K;
        float wv = (c < 64) ? Wl[(size_t)k * 64 + c] : Wr[(size_t)k * 64 + (c - 64)];
        unsigned short h = f2bf(wv);
        Wth[idx] = h;
        Wtl[idx] = f2bf(wv - bf2f(h));
    }
    if (blockIdx.x == 0 && threadIdx.x < 128)
        biasOut[threadIdx.x] = (threadIdx.x < 64) ? 0.f : bl[threadIdx.x - 64];
}

// ---------------- split-bf16 MFMA GEMM: out[N,128] = A[N,K] @ Wt^T + bias ----------------
// F32SRC=1: A is fp32 (split on the fly). F32SRC=0: A given as bf16 hi/lo pair.

template <int F32SRC>
__launch_bounds__(256)
__global__ void gemm_split(const float* __restrict__ Af,
                           const unsigned short* __restrict__ Ahg,
                           const unsigned short* __restrict__ Alg, int astride,
                           const unsigned short* __restrict__ Wth,
                           const unsigned short* __restrict__ Wtl,
                           const float* __restrict__ bias,
                           float* __restrict__ out, int Kg, int Nn) {
    __shared__ unsigned short Ah[64 * 72], Al[64 * 72], Bh[64 * 72], Bl[64 * 72];
    const int tid = threadIdx.x;
    const int l = tid & 63, w = tid >> 6;
    const int rowbase = blockIdx.x * 64;
    const int cy = blockIdx.y;
    f32x4 acc[4] = {};

    for (int k0 = 0; k0 < Kg; k0 += 64) {
        if (k0) __syncthreads();
        if (F32SRC) {
#pragma unroll
            for (int q = 0; q < 4; ++q) {
                int lin = q * 256 + tid;     // 1024 float4 = 64 rows x 64 k
                int row = lin >> 4;
                int kq = (lin & 15) << 2;
                float4 v = make_float4(0.f, 0.f, 0.f, 0.f);
                if (rowbase + row < Nn)
                    v = *(const float4*)(Af + (size_t)(rowbase + row) * Kg + k0 + kq);
                unsigned short h0 = f2bf(v.x), h1 = f2bf(v.y), h2 = f2bf(v.z), h3 = f2bf(v.w);
                *(ushort4*)&Ah[row * 72 + kq] = make_ushort4(h0, h1, h2, h3);
                *(ushort4*)&Al[row * 72 + kq] =
                    make_ushort4(f2bf(v.x - bf2f(h0)), f2bf(v.y - bf2f(h1)),
                                 f2bf(v.z - bf2f(h2)), f2bf(v.w - bf2f(h3)));
            }
        } else {
#pragma unroll
            for (int q = 0; q < 2; ++q) {
                int lin = q * 256 + tid;     // 512 ushort8 = 64 rows x 64 k
                int row = lin >> 3;
                int k8 = (lin & 7) << 3;
                short8 vh = {}, vl = {};
                if (rowbase + row < Nn) {
                    vh = *(const short8*)(Ahg + (size_t)(rowbase + row) * astride + k0 + k8);
                    vl = *(const short8*)(Alg + (size_t)(rowbase + row) * astride + k0 + k8);
                }
                *(short8*)&Ah[row * 72 + k8] = vh;
                *(short8*)&Al[row * 72 + k8] = vl;
            }
        }
#pragma unroll
        for (int q = 0; q < 2; ++q) {
            int lin = q * 256 + tid;
            int c = lin >> 3;
            int k8 = (lin & 7) << 3;
            *(short8*)&Bh[c * 72 + k8] =
                *(const short8*)(Wth + (size_t)(cy * 64 + c) * Kg + k0 + k8);
            *(short8*)&Bl[c * 72 + k8] =
                *(const short8*)(Wtl + (size_t)(cy * 64 + c) * Kg + k0 + k8);
        }
        __syncthreads();

        const int ar = (w * 16 + (l & 15)) * 72;
        const int kofs = (l >> 4) * 8;
#pragma unroll
        for (int kk = 0; kk < 64; kk += 32) {
            short8 a_h = *(const short8*)&Ah[ar + kk + kofs];
            short8 a_l = *(const short8*)&Al[ar + kk + kofs];
#pragma unroll
            for (int ct = 0; ct < 4; ++ct) {
                const int br = (ct * 16 + (l & 15)) * 72 + kk + kofs;
                short8 b_h = *(const short8*)&Bh[br];
                short8 b_l = *(const short8*)&Bl[br];
                acc[ct] = __builtin_amdgcn_mfma_f32_16x16x32_bf16(a_h, b_h, acc[ct], 0, 0, 0);
                acc[ct] = __builtin_amdgcn_mfma_f32_16x16x32_bf16(a_h, b_l, acc[ct], 0, 0, 0);
                acc[ct] = __builtin_amdgcn_mfma_f32_16x16x32_bf16(a_l, b_h, acc[ct], 0, 0, 0);
            }
        }
    }
    // epilogue: C col = lane&15, row = (lane>>4)*4 + i  (verified m89 layout)
    const int r0 = rowbase + w * 16 + ((l >> 4) << 2);
#pragma unroll
    for (int ct = 0; ct < 4; ++ct) {
        int colg = cy * 64 + ct * 16 + (l & 15);
        float b = bias[colg];
#pragma unroll
        for (int i = 0; i < 4; ++i) {
            int rr = r0 + i;
            if (rr < Nn) out[(size_t)rr * 128 + colg] = acc[ct][i] + b;
        }
    }
}

// ---------------- CSR aggregate + finalize: relu(agg(TL)/deg + TR) ----------------
// FINAL=1: write fp32 to outf.  FINAL=0: write split-bf16 state for next layer.

template <int FINAL>
__launch_bounds__(256)
__global__ void sage_agg2(const float* __restrict__ TLTR,
                          const int* __restrict__ rowptr, const int* __restrict__ col,
                          float* __restrict__ outf,
                          unsigned short* __restrict__ Sh, unsigned short* __restrict__ Sl,
                          int n) {
    int node = blockIdx.x * 4 + (threadIdx.x >> 6);
    int lane = threadIdx.x & 63;
    if (node >= n) return;
    int s = rowptr[node], e = rowptr[node + 1];
    float acc = 0.f;
    for (int i = s; i < e; i += 64) {
        int nch = min(64, e - i);
        int c = (i + lane < e) ? col[i + lane] : 0;
        int j = 0;
        for (; j + 4 <= nch; j += 4) {
            int i0 = __shfl(c, j, 64);
            int i1 = __shfl(c, j + 1, 64);
            int i2 = __shfl(c, j + 2, 64);
            int i3 = __shfl(c, j + 3, 64);
            float t0 = TLTR[(size_t)i0 * 128 + lane];
            float t1 = TLTR[(size_t)i1 * 128 + lane];
            float t2 = TLTR[(size_t)i2 * 128 + lane];
            float t3 = TLTR[(size_t)i3 * 128 + lane];
            acc += t0 + t1 + t2 + t3;
        }
        for (; j < nch; ++j) {
            int ix = __shfl(c, j, 64);
            acc += TLTR[(size_t)ix * 128 + lane];
        }
    }
    int deg = e - s;
    float v = acc / (float)max(deg, 1) + TLTR[(size_t)node * 128 + 64 + lane];
    v = fmaxf(v, 0.f);
    if (FINAL) {
        outf[(size_t)node * 64 + lane] = v;
    } else {
        unsigned short h = f2bf(v);
        Sh[(size_t)node * 64 + lane] = h;
        Sl[(size_t)node * 64 + lane] = f2bf(v - bf2f(h));
    }
}

// ---------------- reparameterize + global mean pool ----------------

__launch_bounds__(256)
__global__ void pool_z(const float* __restrict__ mean, const float* __restrict__ logv,
                       const float* __restrict__ eps, const int* __restrict__ batch,
                       float* __restrict__ gsum, int* __restrict__ gcnt, int n) {
    const int CHUNK = 512;
    int wv = threadIdx.x >> 6, lane = threadIdx.x & 63;
    int start = blockIdx.x * CHUNK + wv * (CHUNK / 4);
    int end = min(start + CHUNK / 4, n);
    if (start >= end) return;
    int gcur = batch[start];
    float acc = 0.f;
    int cnt = 0;
    for (int i = start; i < end; ++i) {
        int g = batch[i];
        if (g != gcur) {
            atomicAdd(&gsum[(size_t)gcur * 64 + lane], acc);
            if (lane == 0) atomicAdd(&gcnt[gcur], cnt);
            acc = 0.f;
            cnt = 0;
            gcur = g;
        }
        size_t o = (size_t)i * 64 + lane;
        float z = mean[o] + eps[o] * expf(0.5f * logv[o]);
        acc += z;
        cnt++;
    }
    atomicAdd(&gsum[(size_t)gcur * 64 + lane], acc);
    if (lane == 0) atomicAdd(&gcnt[gcur], cnt);
}

// ---------------- pooled -> fc1 -> relu -> fc2 -> log_softmax ----------------

__launch_bounds__(128)
__global__ void head(const float* __restrict__ gsum, const int* __restrict__ gcnt,
                     const float* __restrict__ fc1W, const float* __restrict__ fc1b,
                     const float* __restrict__ fc2W, const float* __restrict__ fc2b,
                     float* __restrict__ out) {
    __shared__ float pooled[64];
    __shared__ float h[128];
    __shared__ float lg[2];
    int g = blockIdx.x, tid = threadIdx.x;
    if (tid < 64) {
        int c = gcnt[g];
        pooled[tid] = gsum[(size_t)g * 64 + tid] / (float)max(c, 1);
    }
    __syncthreads();
    float acc = fc1b[tid];
    for (int k = 0; k < 64; ++k) acc = fmaf(pooled[k], fc1W[k * 128 + tid], acc);
    h[tid] = fmaxf(acc, 0.f);
    __syncthreads();
    if (tid < 2) {
        float a = fc2b[tid];
        for (int k = 0; k < 128; ++k) a = fmaf(h[k], fc2W[k * 2 + tid], a);
        lg[tid] = a;
    }
    __syncthreads();
    if (tid < 2) {
        float m = fmaxf(lg[0], lg[1]);
        float lse = m + logf(expf(lg[0] - m) + expf(lg[1] - m));
        out[(size_t)g * 2 + tid] = lg[tid] - lse;
    }
}

extern "C" void kernel_launch(void* const* d_in, const int* in_sizes, int n_in,
                              void* d_out, int out_size, void* d_ws, size_t ws_size,
                              hipStream_t stream) {
    const int N = in_sizes[19];
    const int E = in_sizes[18] / 2;
    const int G = (out_size - 2 * N * NH) / NCLS;

    const float* x    = (const float*)d_in[0];
    const float* eps  = (const float*)d_in[1];
    const float* m0Wl = (const float*)d_in[2];
    const float* m0bl = (const float*)d_in[3];
    const float* m0Wr = (const float*)d_in[4];
    const float* mRWl = (const float*)d_in[5];
    const float* mRbl = (const float*)d_in[6];
    const float* mRWr = (const float*)d_in[7];
    const float* v0Wl = (const float*)d_in[8];
    const float* v0bl = (const float*)d_in[9];
    const float* v0Wr = (const float*)d_in[10];
    const float* vRWl = (const float*)d_in[11];
    const float* vRbl = (const float*)d_in[12];
    const float* vRWr = (const float*)d_in[13];
    const float* fc1W = (const float*)d_in[14];
    const float* fc1b = (const float*)d_in[15];
    const float* fc2W = (const float*)d_in[16];
    const float* fc2b = (const float*)d_in[17];
    const int* eidx   = (const int*)d_in[18];
    const int* batch  = (const int*)d_in[19];
    const int* srcI = eidx;
    const int* dstI = eidx + E;

    float* out_ls = (float*)d_out;
    float* out_mean = out_ls + (size_t)G * NCLS;
    float* out_lv = out_mean + (size_t)N * NH;
    // split-bf16 next-layer state lives in the (not yet final) d_out region
    unsigned short* Sh_m = (unsigned short*)out_mean;
    unsigned short* Sl_m = Sh_m + (size_t)N * NH;
    unsigned short* Sh_v = (unsigned short*)out_lv;
    unsigned short* Sl_v = Sh_v + (size_t)N * NH;

    char* w = (char*)d_ws;
    auto alloc = [&](size_t bytes) {
        char* p = w;
        w += (bytes + 255) & ~(size_t)255;
        return p;
    };
    int* deg = (int*)alloc((size_t)N * 4);
    int* rowptr = (int*)alloc((size_t)(N + 1) * 4);
    int* cursor = (int*)alloc((size_t)N * 4);
    int* bsum = (int*)alloc(256 * 4);
    int* boff = (int*)alloc(256 * 4);
    int* col = (int*)alloc((size_t)E * 4);
    float* TLTR = (float*)alloc((size_t)N * 128 * 4);
    unsigned short* w0h = (unsigned short*)alloc(2 * 128 * 128 * 2);  // [mean|var] layer0
    unsigned short* w0l = (unsigned short*)alloc(2 * 128 * 128 * 2);
    unsigned short* wlh = (unsigned short*)alloc(4 * 128 * 64 * 2);   // layers 1-2, m/v
    unsigned short* wll = (unsigned short*)alloc(4 * 128 * 64 * 2);
    float* biasAll = (float*)alloc(6 * 128 * 4);  // [m0|v0|m1|v1|m2|v2]
    float* gsum = (float*)alloc((size_t)G * 64 * 4);
    int* gcnt = (int*)alloc((size_t)G * 4);
    (void)ws_size;
    (void)n_in;

    const int nbE = (E + 255) / 256;
    const int nbScan = (N + 1023) / 1024;

    // CSR build (reused by all convs)
    hipMemsetAsync(deg, 0, (size_t)N * 4, stream);
    count_deg<<<nbE, 256, 0, stream>>>(dstI, deg, E);
    scan1<<<nbScan, 256, 0, stream>>>(deg, rowptr, bsum, N);
    scan2<<<1, 256, 0, stream>>>(bsum, boff, nbScan);
    scan3<<<(N + 256) / 256 + 1, 256, 0, stream>>>(rowptr, boff, N, E);
    hipMemsetAsync(cursor, 0, (size_t)N * 4, stream);
    fill_csr<<<nbE, 256, 0, stream>>>(srcI, dstI, rowptr, cursor, col, E);

    // weight prep (split bf16, transposed, [TL|TR] with bias folded)
    prep_w<<<64, 256, 0, stream>>>(m0Wl, m0Wr, m0bl, 128, w0h, w0l, biasAll);
    prep_w<<<64, 256, 0, stream>>>(v0Wl, v0Wr, v0bl, 128, w0h + 128 * 128, w0l + 128 * 128,
                                   biasAll + 128);
    for (int i = 0; i < 2; ++i) {
        prep_w<<<32, 256, 0, stream>>>(mRWl + (size_t)i * 4096, mRWr + (size_t)i * 4096,
                                       mRbl + (size_t)i * 64, 64,
                                       wlh + (size_t)(2 * i) * 8192, wll + (size_t)(2 * i) * 8192,
                                       biasAll + (2 + 2 * i) * 128);
        prep_w<<<32, 256, 0, stream>>>(vRWl + (size_t)i * 4096, vRWr + (size_t)i * 4096,
                                       vRbl + (size_t)i * 64, 64,
                                       wlh + (size_t)(2 * i + 1) * 8192,
                                       wll + (size_t)(2 * i + 1) * 8192,
                                       biasAll + (2 + 2 * i + 1) * 128);
    }

    const int nbR = (N + 63) / 64;
    const int nbAgg = (N + 3) / 4;
    dim3 gg(nbR, 2);

    // layer 0 (K=128, fp32 source)
    gemm_split<1><<<gg, 256, 0, stream>>>(x, nullptr, nullptr, 0, w0h, w0l, biasAll, TLTR, 128, N);
    sage_agg2<0><<<nbAgg, 256, 0, stream>>>(TLTR, rowptr, col, nullptr, Sh_m, Sl_m, N);
    gemm_split<1><<<gg, 256, 0, stream>>>(x, nullptr, nullptr, 0, w0h + 128 * 128,
                                          w0l + 128 * 128, biasAll + 128, TLTR, 128, N);
    sage_agg2<0><<<nbAgg, 256, 0, stream>>>(TLTR, rowptr, col, nullptr, Sh_v, Sl_v, N);

    // layers 1..2 (K=64, split-bf16 source)
    for (int i = 0; i < 2; ++i) {
        const bool fin = (i == 1);
        gemm_split<0><<<gg, 256, 0, stream>>>(nullptr, Sh_m, Sl_m, 64,
                                              wlh + (size_t)(2 * i) * 8192,
                                              wll + (size_t)(2 * i) * 8192,
                                              biasAll + (2 + 2 * i) * 128, TLTR, 64, N);
        if (fin)
            sage_agg2<1><<<nbAgg, 256, 0, stream>>>(TLTR, rowptr, col, out_mean, nullptr, nullptr, N);
        else
            sage_agg2<0><<<nbAgg, 256, 0, stream>>>(TLTR, rowptr, col, nullptr, Sh_m, Sl_m, N);
        gemm_split<0><<<gg, 256, 0, stream>>>(nullptr, Sh_v, Sl_v, 64,
                                              wlh + (size_t)(2 * i + 1) * 8192,
                                              wll + (size_t)(2 * i + 1) * 8192,
                                              biasAll + (2 + 2 * i + 1) * 128, TLTR, 64, N);
        if (fin)
            sage_agg2<1><<<nbAgg, 256, 0, stream>>>(TLTR, rowptr, col, out_lv, nullptr, nullptr, N);
        else
            sage_agg2<0><<<nbAgg, 256, 0, stream>>>(TLTR, rowptr, col, nullptr, Sh_v, Sl_v, N);
    }

    // reparameterize + pool
    hipMemsetAsync(gsum, 0, (size_t)G * 64 * 4, stream);
    hipMemsetAsync(gcnt, 0, (size_t)G * 4, stream);
    pool_z<<<(N + 511) / 512, 256, 0, stream>>>(out_mean, out_lv, eps, batch, gsum, gcnt, N);

    // FC head + log_softmax
    head<<<G, 128, 0, stream>>>(gsum, gcnt, fc1W, fc1b, fc2W, fc2b, out_ls);
}

// Round 3
// 681.026 us; speedup vs baseline: 2.3742x; 1.1640x over previous
//
#include <hip/hip_runtime.h>

#define NH 64
#define NCLS 2

typedef short short8 __attribute__((ext_vector_type(8)));
typedef float f32x4 __attribute__((ext_vector_type(4)));

__device__ inline unsigned short f2bf(float x) {
    unsigned u = __float_as_uint(x);
    unsigned r = (u + 0x7FFFu + ((u >> 16) & 1u)) >> 16;
    return (unsigned short)r;
}
__device__ inline float bf2f(unsigned short h) { return __uint_as_float(((unsigned)h) << 16); }

// ---------------- CSR build ----------------

__global__ void count_deg4(const int* __restrict__ dst, int* __restrict__ deg, int e) {
    int base = (blockIdx.x * 256 + threadIdx.x) * 4;
    if (base + 3 < e) {
        int4 d = *(const int4*)(dst + base);
        atomicAdd(&deg[d.x], 1);
        atomicAdd(&deg[d.y], 1);
        atomicAdd(&deg[d.z], 1);
        atomicAdd(&deg[d.w], 1);
    } else {
        for (int i = base; i < e; ++i) atomicAdd(&deg[dst[i]], 1);
    }
}

__global__ void scan1(const int* __restrict__ in, int* __restrict__ out,
                      int* __restrict__ bsum, int n) {
    __shared__ int s[256];
    int tid = threadIdx.x;
    int base = blockIdx.x * 1024 + tid * 4;
    int v0 = (base + 0 < n) ? in[base + 0] : 0;
    int v1 = (base + 1 < n) ? in[base + 1] : 0;
    int v2 = (base + 2 < n) ? in[base + 2] : 0;
    int v3 = (base + 3 < n) ? in[base + 3] : 0;
    int lsum = v0 + v1 + v2 + v3;
    s[tid] = lsum;
    __syncthreads();
    for (int off = 1; off < 256; off <<= 1) {
        int t = (tid >= off) ? s[tid - off] : 0;
        __syncthreads();
        s[tid] += t;
        __syncthreads();
    }
    int excl = s[tid] - lsum;
    if (base + 0 < n) out[base + 0] = excl;
    if (base + 1 < n) out[base + 1] = excl + v0;
    if (base + 2 < n) out[base + 2] = excl + v0 + v1;
    if (base + 3 < n) out[base + 3] = excl + v0 + v1 + v2;
    if (tid == 255) bsum[blockIdx.x] = s[255];
}

__global__ void scan2(const int* __restrict__ bsum, int* __restrict__ boff, int nb) {
    __shared__ int s[256];
    int tid = threadIdx.x;
    int v = (tid < nb) ? bsum[tid] : 0;
    s[tid] = v;
    __syncthreads();
    for (int off = 1; off < 256; off <<= 1) {
        int t = (tid >= off) ? s[tid - off] : 0;
        __syncthreads();
        s[tid] += t;
        __syncthreads();
    }
    if (tid < nb) boff[tid] = s[tid] - v;
}

__global__ void scan3(int* __restrict__ rowptr, const int* __restrict__ boff,
                      int n, int total) {
    int i = blockIdx.x * 256 + threadIdx.x;
    if (i < n) rowptr[i] += boff[i >> 10];
    else if (i == n) rowptr[n] = total;
}

// range-partitioned fill: only edges with dst in [lo,hi) -> write window stays in L2
__global__ void fill_csr_pass(const int* __restrict__ src, const int* __restrict__ dst,
                              const int* __restrict__ rowptr, int* __restrict__ cursor,
                              int* __restrict__ col, int e, int lo, int hi) {
    int i = blockIdx.x * 256 + threadIdx.x;
    if (i < e) {
        int d = dst[i];
        if (d >= lo && d < hi) {
            int p = atomicAdd(&cursor[d], 1);
            col[rowptr[d] + p] = src[i];
        }
    }
}

// ---------------- weight prep: W^T split bf16, cols = [TL(64) | TR(64)] ----------------

__global__ void prep_w(const float* __restrict__ Wl, const float* __restrict__ Wr,
                       const float* __restrict__ bl, int K,
                       unsigned short* __restrict__ Wth, unsigned short* __restrict__ Wtl,
                       float* __restrict__ biasOut) {
    int tot = 128 * K;
    for (int idx = blockIdx.x * 256 + threadIdx.x; idx < tot; idx += gridDim.x * 256) {
        int c = idx / K, k = idx - c * K;
        float wv = (c < 64) ? Wl[(size_t)k * 64 + c] : Wr[(size_t)k * 64 + (c - 64)];
        unsigned short h = f2bf(wv);
        Wth[idx] = h;
        Wtl[idx] = f2bf(wv - bf2f(h));
    }
    if (blockIdx.x == 0 && threadIdx.x < 128)
        biasOut[threadIdx.x] = (threadIdx.x < 64) ? 0.f : bl[threadIdx.x - 64];
}

// ---------------- split-bf16 MFMA GEMM, all 128 cols per block ----------------
// Output row layout (TLR, ushort, stride 256): [2*c + path] for c in 0..127
//   c<64  : TL (aggregated over neighbors), interleaved mean/var
//   c>=64 : TR (self term + bias),           interleaved mean/var

template <int F32SRC>
__launch_bounds__(256)
__global__ void gemm_split(const float* __restrict__ Af,
                           const unsigned short* __restrict__ Ahg,
                           const unsigned short* __restrict__ Alg,
                           const unsigned short* __restrict__ Wth,
                           const unsigned short* __restrict__ Wtl,
                           const float* __restrict__ bias,
                           unsigned short* __restrict__ TLR, int path, int Kg, int Nn) {
    __shared__ unsigned short Ah[64 * 72], Al[64 * 72], Bh[128 * 72], Bl[128 * 72];
    const int tid = threadIdx.x;
    const int l = tid & 63, w = tid >> 6;
    const int rowbase = blockIdx.x * 64;
    f32x4 acc[8] = {};

    for (int k0 = 0; k0 < Kg; k0 += 64) {
        if (k0) __syncthreads();
        if (F32SRC) {
#pragma unroll
            for (int q = 0; q < 4; ++q) {
                int lin = q * 256 + tid;
                int row = lin >> 4;
                int kq = (lin & 15) << 2;
                float4 v = make_float4(0.f, 0.f, 0.f, 0.f);
                if (rowbase + row < Nn)
                    v = *(const float4*)(Af + (size_t)(rowbase + row) * Kg + k0 + kq);
                unsigned short h0 = f2bf(v.x), h1 = f2bf(v.y), h2 = f2bf(v.z), h3 = f2bf(v.w);
                *(ushort4*)&Ah[row * 72 + kq] = make_ushort4(h0, h1, h2, h3);
                *(ushort4*)&Al[row * 72 + kq] =
                    make_ushort4(f2bf(v.x - bf2f(h0)), f2bf(v.y - bf2f(h1)),
                                 f2bf(v.z - bf2f(h2)), f2bf(v.w - bf2f(h3)));
            }
        } else {
#pragma unroll
            for (int q = 0; q < 2; ++q) {
                int lin = q * 256 + tid;
                int row = lin >> 3;
                int k8 = (lin & 7) << 3;
                short8 vh = {}, vl = {};
                if (rowbase + row < Nn) {
                    vh = *(const short8*)(Ahg + (size_t)(rowbase + row) * 64 + k0 + k8);
                    vl = *(const short8*)(Alg + (size_t)(rowbase + row) * 64 + k0 + k8);
                }
                *(short8*)&Ah[row * 72 + k8] = vh;
                *(short8*)&Al[row * 72 + k8] = vl;
            }
        }
#pragma unroll
        for (int q = 0; q < 4; ++q) {
            int lin = q * 256 + tid;
            int c = lin >> 3;
            int k8 = (lin & 7) << 3;
            *(short8*)&Bh[c * 72 + k8] = *(const short8*)(Wth + (size_t)c * Kg + k0 + k8);
            *(short8*)&Bl[c * 72 + k8] = *(const short8*)(Wtl + (size_t)c * Kg + k0 + k8);
        }
        __syncthreads();

        const int ar = (w * 16 + (l & 15)) * 72;
        const int kofs = (l >> 4) * 8;
#pragma unroll
        for (int kk = 0; kk < 64; kk += 32) {
            short8 a_h = *(const short8*)&Ah[ar + kk + kofs];
            short8 a_l = *(const short8*)&Al[ar + kk + kofs];
#pragma unroll
            for (int ct = 0; ct < 8; ++ct) {
                const int br = (ct * 16 + (l & 15)) * 72 + kk + kofs;
                short8 b_h = *(const short8*)&Bh[br];
                short8 b_l = *(const short8*)&Bl[br];
                acc[ct] = __builtin_amdgcn_mfma_f32_16x16x32_bf16(a_h, b_h, acc[ct], 0, 0, 0);
                acc[ct] = __builtin_amdgcn_mfma_f32_16x16x32_bf16(a_h, b_l, acc[ct], 0, 0, 0);
                acc[ct] = __builtin_amdgcn_mfma_f32_16x16x32_bf16(a_l, b_h, acc[ct], 0, 0, 0);
            }
        }
    }
    const int r0 = rowbase + w * 16 + ((l >> 4) << 2);
#pragma unroll
    for (int ct = 0; ct < 8; ++ct) {
        int c = ct * 16 + (l & 15);
        float b = bias[c];
#pragma unroll
        for (int i = 0; i < 4; ++i) {
            int rr = r0 + i;
            if (rr < Nn) TLR[(size_t)rr * 256 + 2 * c + path] = f2bf(acc[ct][i] + b);
        }
    }
}

// ---------------- fused CSR aggregate for mean+var: relu(agg(TL)/deg + TR) ----------------

template <int FINAL>
__launch_bounds__(256)
__global__ void agg_fused(const unsigned short* __restrict__ TLR,
                          const int* __restrict__ rowptr, const int* __restrict__ col,
                          float* __restrict__ outm, float* __restrict__ outv,
                          unsigned short* __restrict__ Shm, unsigned short* __restrict__ Slm,
                          unsigned short* __restrict__ Shv, unsigned short* __restrict__ Slv,
                          int n) {
    int node = blockIdx.x * 4 + (threadIdx.x >> 6);
    int lane = threadIdx.x & 63;
    if (node >= n) return;
    int s = rowptr[node], e = rowptr[node + 1];
    float am = 0.f, av = 0.f;
    for (int i = s; i < e; i += 64) {
        int nch = min(64, e - i);
        int c = (i + lane < e) ? col[i + lane] : 0;
        int j = 0;
        for (; j + 4 <= nch; j += 4) {
            int i0 = __shfl(c, j, 64);
            int i1 = __shfl(c, j + 1, 64);
            int i2 = __shfl(c, j + 2, 64);
            int i3 = __shfl(c, j + 3, 64);
            unsigned u0 = ((const unsigned*)(TLR + (size_t)i0 * 256))[lane];
            unsigned u1 = ((const unsigned*)(TLR + (size_t)i1 * 256))[lane];
            unsigned u2 = ((const unsigned*)(TLR + (size_t)i2 * 256))[lane];
            unsigned u3 = ((const unsigned*)(TLR + (size_t)i3 * 256))[lane];
            am += bf2f(u0 & 0xffff) + bf2f(u1 & 0xffff) + bf2f(u2 & 0xffff) + bf2f(u3 & 0xffff);
            av += bf2f(u0 >> 16) + bf2f(u1 >> 16) + bf2f(u2 >> 16) + bf2f(u3 >> 16);
        }
        for (; j < nch; ++j) {
            int ix = __shfl(c, j, 64);
            unsigned u = ((const unsigned*)(TLR + (size_t)ix * 256))[lane];
            am += bf2f(u & 0xffff);
            av += bf2f(u >> 16);
        }
    }
    float inv = 1.0f / (float)max(e - s, 1);
    unsigned t = ((const unsigned*)(TLR + (size_t)node * 256))[64 + lane];
    float vm = fmaxf(am * inv + bf2f(t & 0xffff), 0.f);
    float vv = fmaxf(av * inv + bf2f(t >> 16), 0.f);
    size_t o = (size_t)node * 64 + lane;
    if (FINAL) {
        outm[o] = vm;
        outv[o] = vv;
    } else {
        unsigned short hm = f2bf(vm), hv = f2bf(vv);
        Shm[o] = hm;
        Slm[o] = f2bf(vm - bf2f(hm));
        Shv[o] = hv;
        Slv[o] = f2bf(vv - bf2f(hv));
    }
}

// ---------------- reparameterize + global mean pool ----------------

__launch_bounds__(256)
__global__ void pool_z(const float* __restrict__ mean, const float* __restrict__ logv,
                       const float* __restrict__ eps, const int* __restrict__ batch,
                       float* __restrict__ gsum, int* __restrict__ gcnt, int n) {
    const int CHUNK = 512;
    int wv = threadIdx.x >> 6, lane = threadIdx.x & 63;
    int start = blockIdx.x * CHUNK + wv * (CHUNK / 4);
    int end = min(start + CHUNK / 4, n);
    if (start >= end) return;
    int gcur = batch[start];
    float acc = 0.f;
    int cnt = 0;
    for (int i = start; i < end; ++i) {
        int g = batch[i];
        if (g != gcur) {
            atomicAdd(&gsum[(size_t)gcur * 64 + lane], acc);
            if (lane == 0) atomicAdd(&gcnt[gcur], cnt);
            acc = 0.f;
            cnt = 0;
            gcur = g;
        }
        size_t o = (size_t)i * 64 + lane;
        float z = mean[o] + eps[o] * expf(0.5f * logv[o]);
        acc += z;
        cnt++;
    }
    atomicAdd(&gsum[(size_t)gcur * 64 + lane], acc);
    if (lane == 0) atomicAdd(&gcnt[gcur], cnt);
}

// ---------------- pooled -> fc1 -> relu -> fc2 -> log_softmax ----------------

__launch_bounds__(128)
__global__ void head(const float* __restrict__ gsum, const int* __restrict__ gcnt,
                     const float* __restrict__ fc1W, const float* __restrict__ fc1b,
                     const float* __restrict__ fc2W, const float* __restrict__ fc2b,
                     float* __restrict__ out) {
    __shared__ float pooled[64];
    __shared__ float h[128];
    __shared__ float lg[2];
    int g = blockIdx.x, tid = threadIdx.x;
    if (tid < 64) {
        int c = gcnt[g];
        pooled[tid] = gsum[(size_t)g * 64 + tid] / (float)max(c, 1);
    }
    __syncthreads();
    float acc = fc1b[tid];
    for (int k = 0; k < 64; ++k) acc = fmaf(pooled[k], fc1W[k * 128 + tid], acc);
    h[tid] = fmaxf(acc, 0.f);
    __syncthreads();
    if (tid < 2) {
        float a = fc2b[tid];
        for (int k = 0; k < 128; ++k) a = fmaf(h[k], fc2W[k * 2 + tid], a);
        lg[tid] = a;
    }
    __syncthreads();
    if (tid < 2) {
        float m = fmaxf(lg[0], lg[1]);
        float lse = m + logf(expf(lg[0] - m) + expf(lg[1] - m));
        out[(size_t)g * 2 + tid] = lg[tid] - lse;
    }
}

extern "C" void kernel_launch(void* const* d_in, const int* in_sizes, int n_in,
                              void* d_out, int out_size, void* d_ws, size_t ws_size,
                              hipStream_t stream) {
    const int N = in_sizes[19];
    const int E = in_sizes[18] / 2;
    const int G = (out_size - 2 * N * NH) / NCLS;

    const float* x    = (const float*)d_in[0];
    const float* eps  = (const float*)d_in[1];
    const float* m0Wl = (const float*)d_in[2];
    const float* m0bl = (const float*)d_in[3];
    const float* m0Wr = (const float*)d_in[4];
    const float* mRWl = (const float*)d_in[5];
    const float* mRbl = (const float*)d_in[6];
    const float* mRWr = (const float*)d_in[7];
    const float* v0Wl = (const float*)d_in[8];
    const float* v0bl = (const float*)d_in[9];
    const float* v0Wr = (const float*)d_in[10];
    const float* vRWl = (const float*)d_in[11];
    const float* vRbl = (const float*)d_in[12];
    const float* vRWr = (const float*)d_in[13];
    const float* fc1W = (const float*)d_in[14];
    const float* fc1b = (const float*)d_in[15];
    const float* fc2W = (const float*)d_in[16];
    const float* fc2b = (const float*)d_in[17];
    const int* eidx   = (const int*)d_in[18];
    const int* batch  = (const int*)d_in[19];
    const int* srcI = eidx;
    const int* dstI = eidx + E;

    float* out_ls = (float*)d_out;
    float* out_mean = out_ls + (size_t)G * NCLS;
    float* out_lv = out_mean + (size_t)N * NH;
    // split-bf16 inter-layer state lives in the (not yet final) d_out region
    unsigned short* Sh_m = (unsigned short*)out_mean;
    unsigned short* Sl_m = Sh_m + (size_t)N * NH;
    unsigned short* Sh_v = (unsigned short*)out_lv;
    unsigned short* Sl_v = Sh_v + (size_t)N * NH;

    char* w = (char*)d_ws;
    auto alloc = [&](size_t bytes) {
        char* p = w;
        w += (bytes + 255) & ~(size_t)255;
        return p;
    };
    int* deg = (int*)alloc((size_t)N * 4);
    int* rowptr = (int*)alloc((size_t)(N + 1) * 4);
    int* cursor = (int*)alloc((size_t)N * 4);
    int* bsum = (int*)alloc(256 * 4);
    int* boff = (int*)alloc(256 * 4);
    int* col = (int*)alloc((size_t)E * 4);
    unsigned short* TLR = (unsigned short*)alloc((size_t)N * 256 * 2);  // interleaved m/v
    unsigned short* w0h = (unsigned short*)alloc(2 * 128 * 128 * 2);
    unsigned short* w0l = (unsigned short*)alloc(2 * 128 * 128 * 2);
    unsigned short* wlh = (unsigned short*)alloc(4 * 128 * 64 * 2);
    unsigned short* wll = (unsigned short*)alloc(4 * 128 * 64 * 2);
    float* biasAll = (float*)alloc(6 * 128 * 4);
    float* gsum = (float*)alloc((size_t)G * 64 * 4);
    int* gcnt = (int*)alloc((size_t)G * 4);
    (void)ws_size;
    (void)n_in;

    const int nbE = (E + 255) / 256;
    const int nbScan = (N + 1023) / 1024;

    // CSR build (graph reused by all 3 layers)
    hipMemsetAsync(deg, 0, (size_t)N * 4, stream);
    count_deg4<<<(E + 1023) / 1024, 256, 0, stream>>>(dstI, deg, E);
    scan1<<<nbScan, 256, 0, stream>>>(deg, rowptr, bsum, N);
    scan2<<<1, 256, 0, stream>>>(bsum, boff, nbScan);
    scan3<<<(N + 256) / 256 + 1, 256, 0, stream>>>(rowptr, boff, N, E);
    hipMemsetAsync(cursor, 0, (size_t)N * 4, stream);
    for (int p = 0; p < 4; ++p) {
        int lo = (int)((long long)p * N / 4);
        int hi = (int)((long long)(p + 1) * N / 4);
        fill_csr_pass<<<nbE, 256, 0, stream>>>(srcI, dstI, rowptr, cursor, col, E, lo, hi);
    }

    // weight prep
    prep_w<<<64, 256, 0, stream>>>(m0Wl, m0Wr, m0bl, 128, w0h, w0l, biasAll);
    prep_w<<<64, 256, 0, stream>>>(v0Wl, v0Wr, v0bl, 128, w0h + 128 * 128, w0l + 128 * 128,
                                   biasAll + 128);
    for (int i = 0; i < 2; ++i) {
        prep_w<<<32, 256, 0, stream>>>(mRWl + (size_t)i * 4096, mRWr + (size_t)i * 4096,
                                       mRbl + (size_t)i * 64, 64,
                                       wlh + (size_t)(2 * i) * 8192, wll + (size_t)(2 * i) * 8192,
                                       biasAll + (2 + 2 * i) * 128);
        prep_w<<<32, 256, 0, stream>>>(vRWl + (size_t)i * 4096, vRWr + (size_t)i * 4096,
                                       vRbl + (size_t)i * 64, 64,
                                       wlh + (size_t)(2 * i + 1) * 8192,
                                       wll + (size_t)(2 * i + 1) * 8192,
                                       biasAll + (2 + 2 * i + 1) * 128);
    }

    const int nbR = (N + 63) / 64;
    const int nbAgg = (N + 3) / 4;

    // layer 0 (K=128, fp32 source)
    gemm_split<1><<<nbR, 256, 0, stream>>>(x, nullptr, nullptr, w0h, w0l, biasAll, TLR, 0, 128, N);
    gemm_split<1><<<nbR, 256, 0, stream>>>(x, nullptr, nullptr, w0h + 128 * 128, w0l + 128 * 128,
                                           biasAll + 128, TLR, 1, 128, N);
    agg_fused<0><<<nbAgg, 256, 0, stream>>>(TLR, rowptr, col, nullptr, nullptr,
                                            Sh_m, Sl_m, Sh_v, Sl_v, N);

    // layers 1..2 (K=64, split-bf16 source)
    for (int i = 0; i < 2; ++i) {
        const bool fin = (i == 1);
        gemm_split<0><<<nbR, 256, 0, stream>>>(nullptr, Sh_m, Sl_m,
                                               wlh + (size_t)(2 * i) * 8192,
                                               wll + (size_t)(2 * i) * 8192,
                                               biasAll + (2 + 2 * i) * 128, TLR, 0, 64, N);
        gemm_split<0><<<nbR, 256, 0, stream>>>(nullptr, Sh_v, Sl_v,
                                               wlh + (size_t)(2 * i + 1) * 8192,
                                               wll + (size_t)(2 * i + 1) * 8192,
                                               biasAll + (2 + 2 * i + 1) * 128, TLR, 1, 64, N);
        if (fin)
            agg_fused<1><<<nbAgg, 256, 0, stream>>>(TLR, rowptr, col, out_mean, out_lv,
                                                    nullptr, nullptr, nullptr, nullptr, N);
        else
            agg_fused<0><<<nbAgg, 256, 0, stream>>>(TLR, rowptr, col, nullptr, nullptr,
                                                    Sh_m, Sl_m, Sh_v, Sl_v, N);
    }

    // reparameterize + pool
    hipMemsetAsync(gsum, 0, (size_t)G * 64 * 4, stream);
    hipMemsetAsync(gcnt, 0, (size_t)G * 4, stream);
    pool_z<<<(N + 511) / 512, 256, 0, stream>>>(out_mean, out_lv, eps, batch, gsum, gcnt, N);

    // FC head + log_softmax
    head<<<G, 128, 0, stream>>>(gsum, gcnt, fc1W, fc1b, fc2W, fc2b, out_ls);
}

// Round 4
// 651.029 us; speedup vs baseline: 2.4836x; 1.0461x over previous
//
#include <hip/hip_runtime.h>

#define NH 64
#define NCLS 2

typedef short short8 __attribute__((ext_vector_type(8)));
typedef float f32x4 __attribute__((ext_vector_type(4)));

__device__ inline unsigned short f2bf(float x) {
    unsigned u = __float_as_uint(x);
    unsigned r = (u + 0x7FFFu + ((u >> 16) & 1u)) >> 16;
    return (unsigned short)r;
}
__device__ inline float bf2f(unsigned short h) { return __uint_as_float(((unsigned)h) << 16); }
__device__ inline float bf2f_u(unsigned h) { return __uint_as_float(h << 16); }

// ---------------- CSR build ----------------

__global__ void count_deg4(const int* __restrict__ dst, int* __restrict__ deg, int e) {
    int base = (blockIdx.x * 256 + threadIdx.x) * 4;
    if (base + 3 < e) {
        int4 d = *(const int4*)(dst + base);
        atomicAdd(&deg[d.x], 1);
        atomicAdd(&deg[d.y], 1);
        atomicAdd(&deg[d.z], 1);
        atomicAdd(&deg[d.w], 1);
    } else {
        for (int i = base; i < e; ++i) atomicAdd(&deg[dst[i]], 1);
    }
}

__global__ void scan1(const int* __restrict__ in, int* __restrict__ out,
                      int* __restrict__ bsum, int n) {
    __shared__ int s[256];
    int tid = threadIdx.x;
    int base = blockIdx.x * 1024 + tid * 4;
    int v0 = (base + 0 < n) ? in[base + 0] : 0;
    int v1 = (base + 1 < n) ? in[base + 1] : 0;
    int v2 = (base + 2 < n) ? in[base + 2] : 0;
    int v3 = (base + 3 < n) ? in[base + 3] : 0;
    int lsum = v0 + v1 + v2 + v3;
    s[tid] = lsum;
    __syncthreads();
    for (int off = 1; off < 256; off <<= 1) {
        int t = (tid >= off) ? s[tid - off] : 0;
        __syncthreads();
        s[tid] += t;
        __syncthreads();
    }
    int excl = s[tid] - lsum;
    if (base + 0 < n) out[base + 0] = excl;
    if (base + 1 < n) out[base + 1] = excl + v0;
    if (base + 2 < n) out[base + 2] = excl + v0 + v1;
    if (base + 3 < n) out[base + 3] = excl + v0 + v1 + v2;
    if (tid == 255) bsum[blockIdx.x] = s[255];
}

__global__ void scan2(const int* __restrict__ bsum, int* __restrict__ boff, int nb) {
    __shared__ int s[256];
    int tid = threadIdx.x;
    int v = (tid < nb) ? bsum[tid] : 0;
    s[tid] = v;
    __syncthreads();
    for (int off = 1; off < 256; off <<= 1) {
        int t = (tid >= off) ? s[tid - off] : 0;
        __syncthreads();
        s[tid] += t;
        __syncthreads();
    }
    if (tid < nb) boff[tid] = s[tid] - v;
}

__global__ void scan3(int* __restrict__ rowptr, const int* __restrict__ boff,
                      int n, int total) {
    int i = blockIdx.x * 256 + threadIdx.x;
    if (i < n) rowptr[i] += boff[i >> 10];
    else if (i == n) rowptr[n] = total;
}

// range-partitioned fill: only edges with dst in [lo,hi) -> write window stays in L2
__global__ void fill_csr_pass(const int* __restrict__ src, const int* __restrict__ dst,
                              const int* __restrict__ rowptr, int* __restrict__ cursor,
                              int* __restrict__ col, int e, int lo, int hi) {
    int i = blockIdx.x * 256 + threadIdx.x;
    if (i < e) {
        int d = dst[i];
        if (d >= lo && d < hi) {
            int p = atomicAdd(&cursor[d], 1);
            col[rowptr[d] + p] = src[i];
        }
    }
}

// ---------------- weight prep: W^T split bf16, cols = [TL(64) | TR(64)] ----------------

__global__ void prep_w(const float* __restrict__ Wl, const float* __restrict__ Wr,
                       const float* __restrict__ bl, int K,
                       unsigned short* __restrict__ Wth, unsigned short* __restrict__ Wtl,
                       float* __restrict__ biasOut) {
    int tot = 128 * K;
    for (int idx = blockIdx.x * 256 + threadIdx.x; idx < tot; idx += gridDim.x * 256) {
        int c = idx / K, k = idx - c * K;
        float wv = (c < 64) ? Wl[(size_t)k * 64 + c] : Wr[(size_t)k * 64 + (c - 64)];
        unsigned short h = f2bf(wv);
        Wth[idx] = h;
        Wtl[idx] = f2bf(wv - bf2f(h));
    }
    if (blockIdx.x == 0 && threadIdx.x < 128)
        biasOut[threadIdx.x] = (threadIdx.x < 64) ? 0.f : bl[threadIdx.x - 64];
}

// ---------------- dual-path split-bf16 MFMA GEMM ----------------
// Computes BOTH mean and var paths per block; A staged once (layer0) or both states.
// Output TLRu[r*128 + c] = bf16(mean) | bf16(var)<<16 ; c<64: TL, c>=64: TR(+bias).

template <int F32SRC>
__launch_bounds__(256)
__global__ void gemm_dual(const float* __restrict__ Af,
                          const unsigned short* __restrict__ Ahm,
                          const unsigned short* __restrict__ Alm,
                          const unsigned short* __restrict__ Ahv,
                          const unsigned short* __restrict__ Alv,
                          const unsigned short* __restrict__ Wh,  // [2][128*Kg]
                          const unsigned short* __restrict__ Wl,  // [2][128*Kg]
                          const float* __restrict__ bias,         // [2][128]
                          unsigned* __restrict__ TLRu, int Kg, int Nn) {
    constexpr int NA = F32SRC ? 1 : 2;
    __shared__ unsigned short Ah[NA][64 * 72], Al[NA][64 * 72];
    __shared__ unsigned short Bh[128 * 72], Bl[128 * 72];
    const int tid = threadIdx.x;
    const int l = tid & 63, w = tid >> 6;
    const int rowbase = blockIdx.x * 64;
    f32x4 acc[2][8] = {};

    for (int k0 = 0; k0 < Kg; k0 += 64) {
        if (k0) __syncthreads();
        if (F32SRC) {
#pragma unroll
            for (int q = 0; q < 4; ++q) {
                int lin = q * 256 + tid;
                int row = lin >> 4;
                int kq = (lin & 15) << 2;
                float4 v = make_float4(0.f, 0.f, 0.f, 0.f);
                if (rowbase + row < Nn)
                    v = *(const float4*)(Af + (size_t)(rowbase + row) * Kg + k0 + kq);
                unsigned short h0 = f2bf(v.x), h1 = f2bf(v.y), h2 = f2bf(v.z), h3 = f2bf(v.w);
                *(ushort4*)&Ah[0][row * 72 + kq] = make_ushort4(h0, h1, h2, h3);
                *(ushort4*)&Al[0][row * 72 + kq] =
                    make_ushort4(f2bf(v.x - bf2f(h0)), f2bf(v.y - bf2f(h1)),
                                 f2bf(v.z - bf2f(h2)), f2bf(v.w - bf2f(h3)));
            }
        } else {
#pragma unroll
            for (int st = 0; st < 2; ++st) {
                const unsigned short* Hs = st ? Ahv : Ahm;
                const unsigned short* Ls = st ? Alv : Alm;
#pragma unroll
                for (int q = 0; q < 2; ++q) {
                    int lin = q * 256 + tid;
                    int row = lin >> 3;
                    int k8 = (lin & 7) << 3;
                    short8 vh = {}, vl = {};
                    if (rowbase + row < Nn) {
                        vh = *(const short8*)(Hs + (size_t)(rowbase + row) * 64 + k0 + k8);
                        vl = *(const short8*)(Ls + (size_t)(rowbase + row) * 64 + k0 + k8);
                    }
                    *(short8*)&Ah[st < NA ? st : 0][row * 72 + k8] = vh;
                    *(short8*)&Al[st < NA ? st : 0][row * 72 + k8] = vl;
                }
            }
        }
#pragma unroll
        for (int p = 0; p < 2; ++p) {
            if (p) __syncthreads();  // protect B before restaging
#pragma unroll
            for (int q = 0; q < 4; ++q) {
                int lin = q * 256 + tid;
                int c = lin >> 3;
                int k8 = (lin & 7) << 3;
                *(short8*)&Bh[c * 72 + k8] =
                    *(const short8*)(Wh + (size_t)p * 128 * Kg + (size_t)c * Kg + k0 + k8);
                *(short8*)&Bl[c * 72 + k8] =
                    *(const short8*)(Wl + (size_t)p * 128 * Kg + (size_t)c * Kg + k0 + k8);
            }
            __syncthreads();
            const int ai = F32SRC ? 0 : p;
            const int ar = (w * 16 + (l & 15)) * 72;
            const int kofs = (l >> 4) * 8;
#pragma unroll
            for (int kk = 0; kk < 64; kk += 32) {
                short8 a_h = *(const short8*)&Ah[ai][ar + kk + kofs];
                short8 a_l = *(const short8*)&Al[ai][ar + kk + kofs];
#pragma unroll
                for (int ct = 0; ct < 8; ++ct) {
                    const int br = (ct * 16 + (l & 15)) * 72 + kk + kofs;
                    short8 b_h = *(const short8*)&Bh[br];
                    short8 b_l = *(const short8*)&Bl[br];
                    acc[p][ct] = __builtin_amdgcn_mfma_f32_16x16x32_bf16(a_h, b_h, acc[p][ct], 0, 0, 0);
                    acc[p][ct] = __builtin_amdgcn_mfma_f32_16x16x32_bf16(a_h, b_l, acc[p][ct], 0, 0, 0);
                    acc[p][ct] = __builtin_amdgcn_mfma_f32_16x16x32_bf16(a_l, b_h, acc[p][ct], 0, 0, 0);
                }
            }
        }
    }
    const int r0 = rowbase + w * 16 + ((l >> 4) << 2);
#pragma unroll
    for (int ct = 0; ct < 8; ++ct) {
        int c = ct * 16 + (l & 15);
        float b0 = bias[c];
        float b1 = bias[128 + c];
#pragma unroll
        for (int i = 0; i < 4; ++i) {
            int rr = r0 + i;
            if (rr < Nn) {
                unsigned hm = f2bf(acc[0][ct][i] + b0);
                unsigned hv = f2bf(acc[1][ct][i] + b1);
                TLRu[(size_t)rr * 128 + c] = hm | (hv << 16);
            }
        }
    }
}

// ---------------- fused CSR aggregate (mean+var): relu(agg(TL)/deg + TR) ----------------
// quad-gather: lane = q*16+sub ; quad q handles neighbor j+q, sub covers 4 features (uint4)

template <int FINAL>
__launch_bounds__(256)
__global__ void agg_fused(const unsigned* __restrict__ TLRu,
                          const int* __restrict__ rowptr, const int* __restrict__ col,
                          float* __restrict__ outm, float* __restrict__ outv,
                          unsigned short* __restrict__ Shm, unsigned short* __restrict__ Slm,
                          unsigned short* __restrict__ Shv, unsigned short* __restrict__ Slv,
                          int n) {
    int node = blockIdx.x * 4 + (threadIdx.x >> 6);
    if (node >= n) return;
    int lane = threadIdx.x & 63;
    int q = lane >> 4, sub = lane & 15;
    int s = rowptr[node], e = rowptr[node + 1];
    float am0 = 0, am1 = 0, am2 = 0, am3 = 0;
    float av0 = 0, av1 = 0, av2 = 0, av3 = 0;
    int i = s;
    for (; i + 64 <= e; i += 64) {
        int c = col[i + lane];
#pragma unroll
        for (int j = 0; j < 64; j += 8) {
            int ca = __shfl(c, j + q, 64);
            int cb = __shfl(c, j + 4 + q, 64);
            uint4 ua = ((const uint4*)(TLRu + (size_t)ca * 128))[sub];
            uint4 ub = ((const uint4*)(TLRu + (size_t)cb * 128))[sub];
            am0 += bf2f_u(ua.x & 0xffff) + bf2f_u(ub.x & 0xffff);
            av0 += bf2f_u(ua.x >> 16) + bf2f_u(ub.x >> 16);
            am1 += bf2f_u(ua.y & 0xffff) + bf2f_u(ub.y & 0xffff);
            av1 += bf2f_u(ua.y >> 16) + bf2f_u(ub.y >> 16);
            am2 += bf2f_u(ua.z & 0xffff) + bf2f_u(ub.z & 0xffff);
            av2 += bf2f_u(ua.z >> 16) + bf2f_u(ub.z >> 16);
            am3 += bf2f_u(ua.w & 0xffff) + bf2f_u(ub.w & 0xffff);
            av3 += bf2f_u(ua.w >> 16) + bf2f_u(ub.w >> 16);
        }
    }
    int rem = e - i;
    if (rem > 0) {
        int c = (i + lane < e) ? col[i + lane] : 0;
        for (int j = 0; j < rem; j += 4) {
            int ca = __shfl(c, j + q, 64);
            if (j + q < rem) {
                uint4 ua = ((const uint4*)(TLRu + (size_t)ca * 128))[sub];
                am0 += bf2f_u(ua.x & 0xffff);
                av0 += bf2f_u(ua.x >> 16);
                am1 += bf2f_u(ua.y & 0xffff);
                av1 += bf2f_u(ua.y >> 16);
                am2 += bf2f_u(ua.z & 0xffff);
                av2 += bf2f_u(ua.z >> 16);
                am3 += bf2f_u(ua.w & 0xffff);
                av3 += bf2f_u(ua.w >> 16);
            }
        }
    }
#define RED_(x)                      \
    x += __shfl_xor(x, 16, 64);      \
    x += __shfl_xor(x, 32, 64);
    RED_(am0) RED_(am1) RED_(am2) RED_(am3)
    RED_(av0) RED_(av1) RED_(av2) RED_(av3)
#undef RED_
    float inv = 1.0f / (float)max(e - s, 1);
    uint4 t = ((const uint4*)(TLRu + (size_t)node * 128 + 64))[sub];
    float vm0 = fmaxf(am0 * inv + bf2f_u(t.x & 0xffff), 0.f);
    float vv0 = fmaxf(av0 * inv + bf2f_u(t.x >> 16), 0.f);
    float vm1 = fmaxf(am1 * inv + bf2f_u(t.y & 0xffff), 0.f);
    float vv1 = fmaxf(av1 * inv + bf2f_u(t.y >> 16), 0.f);
    float vm2 = fmaxf(am2 * inv + bf2f_u(t.z & 0xffff), 0.f);
    float vv2 = fmaxf(av2 * inv + bf2f_u(t.z >> 16), 0.f);
    float vm3 = fmaxf(am3 * inv + bf2f_u(t.w & 0xffff), 0.f);
    float vv3 = fmaxf(av3 * inv + bf2f_u(t.w >> 16), 0.f);
    if (q == 0) {
        size_t o = (size_t)node * 64 + sub * 4;
        if (FINAL) {
            *(float4*)(outm + o) = make_float4(vm0, vm1, vm2, vm3);
            *(float4*)(outv + o) = make_float4(vv0, vv1, vv2, vv3);
        } else {
            ushort4 hm = make_ushort4(f2bf(vm0), f2bf(vm1), f2bf(vm2), f2bf(vm3));
            ushort4 hv = make_ushort4(f2bf(vv0), f2bf(vv1), f2bf(vv2), f2bf(vv3));
            *(ushort4*)(Shm + o) = hm;
            *(ushort4*)(Shv + o) = hv;
            *(ushort4*)(Slm + o) = make_ushort4(f2bf(vm0 - bf2f(hm.x)), f2bf(vm1 - bf2f(hm.y)),
                                                f2bf(vm2 - bf2f(hm.z)), f2bf(vm3 - bf2f(hm.w)));
            *(ushort4*)(Slv + o) = make_ushort4(f2bf(vv0 - bf2f(hv.x)), f2bf(vv1 - bf2f(hv.y)),
                                                f2bf(vv2 - bf2f(hv.z)), f2bf(vv3 - bf2f(hv.w)));
        }
    }
}

// ---------------- per-group: reparam + mean-pool + fc1 + relu + fc2 + log_softmax ----------------

__launch_bounds__(256)
__global__ void pool_head(const float* __restrict__ mean, const float* __restrict__ logv,
                          const float* __restrict__ eps, const int* __restrict__ batch,
                          const float* __restrict__ fc1W, const float* __restrict__ fc1b,
                          const float* __restrict__ fc2W, const float* __restrict__ fc2b,
                          float* __restrict__ out, int n) {
    __shared__ int se[2];
    __shared__ float4 red[256];
    __shared__ float pooled[64];
    __shared__ float hbuf[128];
    __shared__ float lg[2];
    const int g = blockIdx.x, tid = threadIdx.x;
    if (tid == 0 || tid == 64) {
        int key = g + (tid >> 6);
        int a = 0, b = n;
        while (a < b) {
            int m = (a + b) >> 1;
            if (batch[m] < key) a = m + 1;
            else b = m;
        }
        se[tid >> 6] = a;
    }
    __syncthreads();
    const int s = se[0], e = se[1];
    const int nof = tid >> 4, fq = tid & 15;
    float4 acc = make_float4(0.f, 0.f, 0.f, 0.f);
    for (int i = s + nof; i < e; i += 16) {
        size_t o = (size_t)i * 64 + fq * 4;
        float4 m4 = *(const float4*)(mean + o);
        float4 l4 = *(const float4*)(logv + o);
        float4 e4 = *(const float4*)(eps + o);
        acc.x += m4.x + e4.x * expf(0.5f * l4.x);
        acc.y += m4.y + e4.y * expf(0.5f * l4.y);
        acc.z += m4.z + e4.z * expf(0.5f * l4.z);
        acc.w += m4.w + e4.w * expf(0.5f * l4.w);
    }
    red[tid] = acc;
    __syncthreads();
    if (tid < 16) {
        float4 sum = red[fq];
        for (int j = 1; j < 16; ++j) {
            float4 r = red[j * 16 + fq];
            sum.x += r.x;
            sum.y += r.y;
            sum.z += r.z;
            sum.w += r.w;
        }
        float inv = 1.0f / (float)max(e - s, 1);
        pooled[fq * 4 + 0] = sum.x * inv;
        pooled[fq * 4 + 1] = sum.y * inv;
        pooled[fq * 4 + 2] = sum.z * inv;
        pooled[fq * 4 + 3] = sum.w * inv;
    }
    __syncthreads();
    if (tid < 128) {
        float a = fc1b[tid];
        for (int k = 0; k < 64; ++k) a = fmaf(pooled[k], fc1W[k * 128 + tid], a);
        hbuf[tid] = fmaxf(a, 0.f);
    }
    __syncthreads();
    if (tid < 2) {
        float a = fc2b[tid];
        for (int k = 0; k < 128; ++k) a = fmaf(hbuf[k], fc2W[k * 2 + tid], a);
        lg[tid] = a;
    }
    __syncthreads();
    if (tid < 2) {
        float m = fmaxf(lg[0], lg[1]);
        float lse = m + logf(expf(lg[0] - m) + expf(lg[1] - m));
        out[(size_t)g * 2 + tid] = lg[tid] - lse;
    }
}

extern "C" void kernel_launch(void* const* d_in, const int* in_sizes, int n_in,
                              void* d_out, int out_size, void* d_ws, size_t ws_size,
                              hipStream_t stream) {
    const int N = in_sizes[19];
    const int E = in_sizes[18] / 2;
    const int G = (out_size - 2 * N * NH) / NCLS;

    const float* x    = (const float*)d_in[0];
    const float* eps  = (const float*)d_in[1];
    const float* m0Wl = (const float*)d_in[2];
    const float* m0bl = (const float*)d_in[3];
    const float* m0Wr = (const float*)d_in[4];
    const float* mRWl = (const float*)d_in[5];
    const float* mRbl = (const float*)d_in[6];
    const float* mRWr = (const float*)d_in[7];
    const float* v0Wl = (const float*)d_in[8];
    const float* v0bl = (const float*)d_in[9];
    const float* v0Wr = (const float*)d_in[10];
    const float* vRWl = (const float*)d_in[11];
    const float* vRbl = (const float*)d_in[12];
    const float* vRWr = (const float*)d_in[13];
    const float* fc1W = (const float*)d_in[14];
    const float* fc1b = (const float*)d_in[15];
    const float* fc2W = (const float*)d_in[16];
    const float* fc2b = (const float*)d_in[17];
    const int* eidx   = (const int*)d_in[18];
    const int* batch  = (const int*)d_in[19];
    const int* srcI = eidx;
    const int* dstI = eidx + E;

    float* out_ls = (float*)d_out;
    float* out_mean = out_ls + (size_t)G * NCLS;
    float* out_lv = out_mean + (size_t)N * NH;
    // split-bf16 inter-layer state lives in the (not yet final) d_out region
    unsigned short* Sh_m = (unsigned short*)out_mean;
    unsigned short* Sl_m = Sh_m + (size_t)N * NH;
    unsigned short* Sh_v = (unsigned short*)out_lv;
    unsigned short* Sl_v = Sh_v + (size_t)N * NH;

    char* w = (char*)d_ws;
    auto alloc = [&](size_t bytes) {
        char* p = w;
        w += (bytes + 255) & ~(size_t)255;
        return p;
    };
    int* deg = (int*)alloc((size_t)N * 4);
    int* rowptr = (int*)alloc((size_t)(N + 1) * 4);
    int* cursor = (int*)alloc((size_t)N * 4);
    int* bsum = (int*)alloc(256 * 4);
    int* boff = (int*)alloc(256 * 4);
    int* col = (int*)alloc((size_t)E * 4);
    unsigned* TLRu = (unsigned*)alloc((size_t)N * 128 * 4);  // packed mean|var
    unsigned short* w0h = (unsigned short*)alloc(2 * 128 * 128 * 2);
    unsigned short* w0l = (unsigned short*)alloc(2 * 128 * 128 * 2);
    unsigned short* wlh = (unsigned short*)alloc(4 * 128 * 64 * 2);
    unsigned short* wll = (unsigned short*)alloc(4 * 128 * 64 * 2);
    float* biasAll = (float*)alloc(6 * 128 * 4);
    (void)ws_size;
    (void)n_in;

    const int nbE = (E + 255) / 256;
    const int nbScan = (N + 1023) / 1024;

    // CSR build (graph reused by all 3 layers)
    hipMemsetAsync(deg, 0, (size_t)N * 4, stream);
    count_deg4<<<(E + 1023) / 1024, 256, 0, stream>>>(dstI, deg, E);
    scan1<<<nbScan, 256, 0, stream>>>(deg, rowptr, bsum, N);
    scan2<<<1, 256, 0, stream>>>(bsum, boff, nbScan);
    scan3<<<(N + 256) / 256 + 1, 256, 0, stream>>>(rowptr, boff, N, E);
    hipMemsetAsync(cursor, 0, (size_t)N * 4, stream);
    for (int p = 0; p < 4; ++p) {
        int lo = (int)((long long)p * N / 4);
        int hi = (int)((long long)(p + 1) * N / 4);
        fill_csr_pass<<<nbE, 256, 0, stream>>>(srcI, dstI, rowptr, cursor, col, E, lo, hi);
    }

    // weight prep
    prep_w<<<64, 256, 0, stream>>>(m0Wl, m0Wr, m0bl, 128, w0h, w0l, biasAll);
    prep_w<<<64, 256, 0, stream>>>(v0Wl, v0Wr, v0bl, 128, w0h + 128 * 128, w0l + 128 * 128,
                                   biasAll + 128);
    for (int i = 0; i < 2; ++i) {
        prep_w<<<32, 256, 0, stream>>>(mRWl + (size_t)i * 4096, mRWr + (size_t)i * 4096,
                                       mRbl + (size_t)i * 64, 64,
                                       wlh + (size_t)(2 * i) * 8192, wll + (size_t)(2 * i) * 8192,
                                       biasAll + (2 + 2 * i) * 128);
        prep_w<<<32, 256, 0, stream>>>(vRWl + (size_t)i * 4096, vRWr + (size_t)i * 4096,
                                       vRbl + (size_t)i * 64, 64,
                                       wlh + (size_t)(2 * i + 1) * 8192,
                                       wll + (size_t)(2 * i + 1) * 8192,
                                       biasAll + (2 + 2 * i + 1) * 128);
    }

    const int nbR = (N + 63) / 64;
    const int nbAgg = (N + 3) / 4;

    // layer 0 (K=128, fp32 source, both paths in one kernel)
    gemm_dual<1><<<nbR, 256, 0, stream>>>(x, nullptr, nullptr, nullptr, nullptr,
                                          w0h, w0l, biasAll, TLRu, 128, N);
    agg_fused<0><<<nbAgg, 256, 0, stream>>>(TLRu, rowptr, col, nullptr, nullptr,
                                            Sh_m, Sl_m, Sh_v, Sl_v, N);

    // layers 1..2 (K=64, split-bf16 state)
    for (int i = 0; i < 2; ++i) {
        const bool fin = (i == 1);
        gemm_dual<0><<<nbR, 256, 0, stream>>>(nullptr, Sh_m, Sl_m, Sh_v, Sl_v,
                                              wlh + (size_t)(2 * i) * 8192,
                                              wll + (size_t)(2 * i) * 8192,
                                              biasAll + (2 + 2 * i) * 128, TLRu, 64, N);
        if (fin)
            agg_fused<1><<<nbAgg, 256, 0, stream>>>(TLRu, rowptr, col, out_mean, out_lv,
                                                    nullptr, nullptr, nullptr, nullptr, N);
        else
            agg_fused<0><<<nbAgg, 256, 0, stream>>>(TLRu, rowptr, col, nullptr, nullptr,
                                                    Sh_m, Sl_m, Sh_v, Sl_v, N);
    }

    // reparam + pool + FC head, one block per graph
    pool_head<<<G, 256, 0, stream>>>(out_mean, out_lv, eps, batch, fc1W, fc1b, fc2W, fc2b,
                                     out_ls, N);
}

// Round 5
// 539.895 us; speedup vs baseline: 2.9948x; 1.2058x over previous
//
#include <hip/hip_runtime.h>

#define NH 64
#define NCLS 2

typedef short short8 __attribute__((ext_vector_type(8)));
typedef float f32x4 __attribute__((ext_vector_type(4)));

__device__ inline unsigned short f2bf(float x) {
    unsigned u = __float_as_uint(x);
    unsigned r = (u + 0x7FFFu + ((u >> 16) & 1u)) >> 16;
    return (unsigned short)r;
}
__device__ inline float bf2f(unsigned short h) { return __uint_as_float(((unsigned)h) << 16); }
__device__ inline float bf2f_u(unsigned h) { return __uint_as_float(h << 16); }

__device__ inline void acc_u4(uint4 u, float4& am, float4& av) {
    am.x += __uint_as_float(u.x << 16);
    av.x += __uint_as_float(u.x & 0xffff0000u);
    am.y += __uint_as_float(u.y << 16);
    av.y += __uint_as_float(u.y & 0xffff0000u);
    am.z += __uint_as_float(u.z << 16);
    av.z += __uint_as_float(u.z & 0xffff0000u);
    am.w += __uint_as_float(u.w << 16);
    av.w += __uint_as_float(u.w & 0xffff0000u);
}

// ---------------- CSR build ----------------

__global__ void count_deg4(const int* __restrict__ dst, int* __restrict__ deg, int e) {
    int base = (blockIdx.x * 256 + threadIdx.x) * 4;
    if (base + 3 < e) {
        int4 d = *(const int4*)(dst + base);
        atomicAdd(&deg[d.x], 1);
        atomicAdd(&deg[d.y], 1);
        atomicAdd(&deg[d.z], 1);
        atomicAdd(&deg[d.w], 1);
    } else {
        for (int i = base; i < e; ++i) atomicAdd(&deg[dst[i]], 1);
    }
}

__global__ void scan1(const int* __restrict__ in, int* __restrict__ out,
                      int* __restrict__ bsum, int n) {
    __shared__ int s[256];
    int tid = threadIdx.x;
    int base = blockIdx.x * 1024 + tid * 4;
    int v0 = (base + 0 < n) ? in[base + 0] : 0;
    int v1 = (base + 1 < n) ? in[base + 1] : 0;
    int v2 = (base + 2 < n) ? in[base + 2] : 0;
    int v3 = (base + 3 < n) ? in[base + 3] : 0;
    int lsum = v0 + v1 + v2 + v3;
    s[tid] = lsum;
    __syncthreads();
    for (int off = 1; off < 256; off <<= 1) {
        int t = (tid >= off) ? s[tid - off] : 0;
        __syncthreads();
        s[tid] += t;
        __syncthreads();
    }
    int excl = s[tid] - lsum;
    if (base + 0 < n) out[base + 0] = excl;
    if (base + 1 < n) out[base + 1] = excl + v0;
    if (base + 2 < n) out[base + 2] = excl + v0 + v1;
    if (base + 3 < n) out[base + 3] = excl + v0 + v1 + v2;
    if (tid == 255) bsum[blockIdx.x] = s[255];
}

__global__ void scan2(const int* __restrict__ bsum, int* __restrict__ boff, int nb) {
    __shared__ int s[256];
    int tid = threadIdx.x;
    int v = (tid < nb) ? bsum[tid] : 0;
    s[tid] = v;
    __syncthreads();
    for (int off = 1; off < 256; off <<= 1) {
        int t = (tid >= off) ? s[tid - off] : 0;
        __syncthreads();
        s[tid] += t;
        __syncthreads();
    }
    if (tid < nb) boff[tid] = s[tid] - v;
}

__global__ void scan3(int* __restrict__ rowptr, const int* __restrict__ boff,
                      int n, int total) {
    int i = blockIdx.x * 256 + threadIdx.x;
    if (i < n) rowptr[i] += boff[i >> 10];
    else if (i == n) rowptr[n] = total;
}

// range-partitioned fill: only edges with dst in [lo,hi) -> write window stays in L2
__global__ void fill_csr_pass(const int* __restrict__ src, const int* __restrict__ dst,
                              const int* __restrict__ rowptr, int* __restrict__ cursor,
                              int* __restrict__ col, int e, int lo, int hi) {
    int i = blockIdx.x * 256 + threadIdx.x;
    if (i < e) {
        int d = dst[i];
        if (d >= lo && d < hi) {
            int p = atomicAdd(&cursor[d], 1);
            col[rowptr[d] + p] = src[i];
        }
    }
}

// ---------------- weight prep: W^T split bf16, cols = [TL(64) | TR(64)] ----------------

__global__ void prep_w(const float* __restrict__ Wl, const float* __restrict__ Wr,
                       const float* __restrict__ bl, int K,
                       unsigned short* __restrict__ Wth, unsigned short* __restrict__ Wtl,
                       float* __restrict__ biasOut) {
    int tot = 128 * K;
    for (int idx = blockIdx.x * 256 + threadIdx.x; idx < tot; idx += gridDim.x * 256) {
        int c = idx / K, k = idx - c * K;
        float wv = (c < 64) ? Wl[(size_t)k * 64 + c] : Wr[(size_t)k * 64 + (c - 64)];
        unsigned short h = f2bf(wv);
        Wth[idx] = h;
        Wtl[idx] = f2bf(wv - bf2f(h));
    }
    if (blockIdx.x == 0 && threadIdx.x < 128)
        biasOut[threadIdx.x] = (threadIdx.x < 64) ? 0.f : bl[threadIdx.x - 64];
}

// ---------------- dual-path split-bf16 MFMA GEMM ----------------
// Output TLRu[r*128 + c] = bf16(mean) | bf16(var)<<16 ; c<64: TL, c>=64: TR(+bias).

template <int F32SRC>
__launch_bounds__(256)
__global__ void gemm_dual(const float* __restrict__ Af,
                          const unsigned short* __restrict__ Ahm,
                          const unsigned short* __restrict__ Alm,
                          const unsigned short* __restrict__ Ahv,
                          const unsigned short* __restrict__ Alv,
                          const unsigned short* __restrict__ Wh,  // [2][128*Kg]
                          const unsigned short* __restrict__ Wl,  // [2][128*Kg]
                          const float* __restrict__ bias,         // [2][128]
                          unsigned* __restrict__ TLRu, int Kg, int Nn) {
    constexpr int NA = F32SRC ? 1 : 2;
    __shared__ unsigned short Ah[NA][64 * 72], Al[NA][64 * 72];
    __shared__ unsigned short Bh[128 * 72], Bl[128 * 72];
    const int tid = threadIdx.x;
    const int l = tid & 63, w = tid >> 6;
    const int rowbase = blockIdx.x * 64;
    f32x4 acc[2][8] = {};

    for (int k0 = 0; k0 < Kg; k0 += 64) {
        if (k0) __syncthreads();
        if (F32SRC) {
#pragma unroll
            for (int q = 0; q < 4; ++q) {
                int lin = q * 256 + tid;
                int row = lin >> 4;
                int kq = (lin & 15) << 2;
                float4 v = make_float4(0.f, 0.f, 0.f, 0.f);
                if (rowbase + row < Nn)
                    v = *(const float4*)(Af + (size_t)(rowbase + row) * Kg + k0 + kq);
                unsigned short h0 = f2bf(v.x), h1 = f2bf(v.y), h2 = f2bf(v.z), h3 = f2bf(v.w);
                *(ushort4*)&Ah[0][row * 72 + kq] = make_ushort4(h0, h1, h2, h3);
                *(ushort4*)&Al[0][row * 72 + kq] =
                    make_ushort4(f2bf(v.x - bf2f(h0)), f2bf(v.y - bf2f(h1)),
                                 f2bf(v.z - bf2f(h2)), f2bf(v.w - bf2f(h3)));
            }
        } else {
#pragma unroll
            for (int st = 0; st < 2; ++st) {
                const unsigned short* Hs = st ? Ahv : Ahm;
                const unsigned short* Ls = st ? Alv : Alm;
#pragma unroll
                for (int q = 0; q < 2; ++q) {
                    int lin = q * 256 + tid;
                    int row = lin >> 3;
                    int k8 = (lin & 7) << 3;
                    short8 vh = {}, vl = {};
                    if (rowbase + row < Nn) {
                        vh = *(const short8*)(Hs + (size_t)(rowbase + row) * 64 + k0 + k8);
                        vl = *(const short8*)(Ls + (size_t)(rowbase + row) * 64 + k0 + k8);
                    }
                    *(short8*)&Ah[st < NA ? st : 0][row * 72 + k8] = vh;
                    *(short8*)&Al[st < NA ? st : 0][row * 72 + k8] = vl;
                }
            }
        }
#pragma unroll
        for (int p = 0; p < 2; ++p) {
            if (p) __syncthreads();  // protect B before restaging
#pragma unroll
            for (int q = 0; q < 4; ++q) {
                int lin = q * 256 + tid;
                int c = lin >> 3;
                int k8 = (lin & 7) << 3;
                *(short8*)&Bh[c * 72 + k8] =
                    *(const short8*)(Wh + (size_t)p * 128 * Kg + (size_t)c * Kg + k0 + k8);
                *(short8*)&Bl[c * 72 + k8] =
                    *(const short8*)(Wl + (size_t)p * 128 * Kg + (size_t)c * Kg + k0 + k8);
            }
            __syncthreads();
            const int ai = F32SRC ? 0 : p;
            const int ar = (w * 16 + (l & 15)) * 72;
            const int kofs = (l >> 4) * 8;
#pragma unroll
            for (int kk = 0; kk < 64; kk += 32) {
                short8 a_h = *(const short8*)&Ah[ai][ar + kk + kofs];
                short8 a_l = *(const short8*)&Al[ai][ar + kk + kofs];
#pragma unroll
                for (int ct = 0; ct < 8; ++ct) {
                    const int br = (ct * 16 + (l & 15)) * 72 + kk + kofs;
                    short8 b_h = *(const short8*)&Bh[br];
                    short8 b_l = *(const short8*)&Bl[br];
                    acc[p][ct] = __builtin_amdgcn_mfma_f32_16x16x32_bf16(a_h, b_h, acc[p][ct], 0, 0, 0);
                    acc[p][ct] = __builtin_amdgcn_mfma_f32_16x16x32_bf16(a_h, b_l, acc[p][ct], 0, 0, 0);
                    acc[p][ct] = __builtin_amdgcn_mfma_f32_16x16x32_bf16(a_l, b_h, acc[p][ct], 0, 0, 0);
                }
            }
        }
    }
    const int r0 = rowbase + w * 16 + ((l >> 4) << 2);
#pragma unroll
    for (int ct = 0; ct < 8; ++ct) {
        int c = ct * 16 + (l & 15);
        float b0 = bias[c];
        float b1 = bias[128 + c];
#pragma unroll
        for (int i = 0; i < 4; ++i) {
            int rr = r0 + i;
            if (rr < Nn) {
                unsigned hm = f2bf(acc[0][ct][i] + b0);
                unsigned hv = f2bf(acc[1][ct][i] + b1);
                TLRu[(size_t)rr * 128 + c] = hm | (hv << 16);
            }
        }
    }
}

// ---------------- fused CSR aggregate (mean+var): relu(agg(TL)/deg + TR) ----------------
// 16-lane group per node; lane sub owns uint4 #sub (features 4sub..4sub+3).
// No shuffles, no cross-lane reduce; neighbors unrolled 8/4-deep for MLP.

template <int FINAL>
__launch_bounds__(256)
__global__ void agg_fused(const unsigned* __restrict__ TLRu,
                          const int* __restrict__ rowptr, const int* __restrict__ col,
                          float* __restrict__ outm, float* __restrict__ outv,
                          unsigned short* __restrict__ Shm, unsigned short* __restrict__ Slm,
                          unsigned short* __restrict__ Shv, unsigned short* __restrict__ Slv,
                          int n) {
    int node = blockIdx.x * 16 + (threadIdx.x >> 4);
    if (node >= n) return;
    const int sub = threadIdx.x & 15;
    const int s = rowptr[node], e = rowptr[node + 1];
    float4 am0 = {0, 0, 0, 0}, av0 = {0, 0, 0, 0};
    float4 am1 = {0, 0, 0, 0}, av1 = {0, 0, 0, 0};
    int j = s;
    for (; j + 8 <= e; j += 8) {
        int c0 = col[j], c1 = col[j + 1], c2 = col[j + 2], c3 = col[j + 3];
        int c4 = col[j + 4], c5 = col[j + 5], c6 = col[j + 6], c7 = col[j + 7];
        uint4 u0 = ((const uint4*)(TLRu + (size_t)c0 * 128))[sub];
        uint4 u1 = ((const uint4*)(TLRu + (size_t)c1 * 128))[sub];
        uint4 u2 = ((const uint4*)(TLRu + (size_t)c2 * 128))[sub];
        uint4 u3 = ((const uint4*)(TLRu + (size_t)c3 * 128))[sub];
        uint4 u4 = ((const uint4*)(TLRu + (size_t)c4 * 128))[sub];
        uint4 u5 = ((const uint4*)(TLRu + (size_t)c5 * 128))[sub];
        uint4 u6 = ((const uint4*)(TLRu + (size_t)c6 * 128))[sub];
        uint4 u7 = ((const uint4*)(TLRu + (size_t)c7 * 128))[sub];
        acc_u4(u0, am0, av0);
        acc_u4(u1, am1, av1);
        acc_u4(u2, am0, av0);
        acc_u4(u3, am1, av1);
        acc_u4(u4, am0, av0);
        acc_u4(u5, am1, av1);
        acc_u4(u6, am0, av0);
        acc_u4(u7, am1, av1);
    }
    if (j + 4 <= e) {
        int c0 = col[j], c1 = col[j + 1], c2 = col[j + 2], c3 = col[j + 3];
        uint4 u0 = ((const uint4*)(TLRu + (size_t)c0 * 128))[sub];
        uint4 u1 = ((const uint4*)(TLRu + (size_t)c1 * 128))[sub];
        uint4 u2 = ((const uint4*)(TLRu + (size_t)c2 * 128))[sub];
        uint4 u3 = ((const uint4*)(TLRu + (size_t)c3 * 128))[sub];
        acc_u4(u0, am0, av0);
        acc_u4(u1, am1, av1);
        acc_u4(u2, am0, av0);
        acc_u4(u3, am1, av1);
        j += 4;
    }
    for (; j < e; ++j) {
        int c0 = col[j];
        uint4 u0 = ((const uint4*)(TLRu + (size_t)c0 * 128))[sub];
        acc_u4(u0, am0, av0);
    }
    am0.x += am1.x; am0.y += am1.y; am0.z += am1.z; am0.w += am1.w;
    av0.x += av1.x; av0.y += av1.y; av0.z += av1.z; av0.w += av1.w;

    float inv = 1.0f / (float)max(e - s, 1);
    uint4 t = ((const uint4*)(TLRu + (size_t)node * 128 + 64))[sub];
    float vm0 = fmaxf(fmaf(am0.x, inv, bf2f_u(t.x & 0xffff)), 0.f);
    float vv0 = fmaxf(fmaf(av0.x, inv, __uint_as_float(t.x & 0xffff0000u)), 0.f);
    float vm1 = fmaxf(fmaf(am0.y, inv, bf2f_u(t.y & 0xffff)), 0.f);
    float vv1 = fmaxf(fmaf(av0.y, inv, __uint_as_float(t.y & 0xffff0000u)), 0.f);
    float vm2 = fmaxf(fmaf(am0.z, inv, bf2f_u(t.z & 0xffff)), 0.f);
    float vv2 = fmaxf(fmaf(av0.z, inv, __uint_as_float(t.z & 0xffff0000u)), 0.f);
    float vm3 = fmaxf(fmaf(am0.w, inv, bf2f_u(t.w & 0xffff)), 0.f);
    float vv3 = fmaxf(fmaf(av0.w, inv, __uint_as_float(t.w & 0xffff0000u)), 0.f);
    size_t o = (size_t)node * 64 + sub * 4;
    if (FINAL) {
        *(float4*)(outm + o) = make_float4(vm0, vm1, vm2, vm3);
        *(float4*)(outv + o) = make_float4(vv0, vv1, vv2, vv3);
    } else {
        ushort4 hm = make_ushort4(f2bf(vm0), f2bf(vm1), f2bf(vm2), f2bf(vm3));
        ushort4 hv = make_ushort4(f2bf(vv0), f2bf(vv1), f2bf(vv2), f2bf(vv3));
        *(ushort4*)(Shm + o) = hm;
        *(ushort4*)(Shv + o) = hv;
        *(ushort4*)(Slm + o) = make_ushort4(f2bf(vm0 - bf2f(hm.x)), f2bf(vm1 - bf2f(hm.y)),
                                            f2bf(vm2 - bf2f(hm.z)), f2bf(vm3 - bf2f(hm.w)));
        *(ushort4*)(Slv + o) = make_ushort4(f2bf(vv0 - bf2f(hv.x)), f2bf(vv1 - bf2f(hv.y)),
                                            f2bf(vv2 - bf2f(hv.z)), f2bf(vv3 - bf2f(hv.w)));
    }
}

// ---------------- per-group: reparam + mean-pool + fc1 + relu + fc2 + log_softmax ----------------

__launch_bounds__(256)
__global__ void pool_head(const float* __restrict__ mean, const float* __restrict__ logv,
                          const float* __restrict__ eps, const int* __restrict__ batch,
                          const float* __restrict__ fc1W, const float* __restrict__ fc1b,
                          const float* __restrict__ fc2W, const float* __restrict__ fc2b,
                          float* __restrict__ out, int n) {
    __shared__ int se[2];
    __shared__ float4 red[256];
    __shared__ float pooled[64];
    __shared__ float hbuf[128];
    __shared__ float lg[2];
    const int g = blockIdx.x, tid = threadIdx.x;
    if (tid == 0 || tid == 64) {
        int key = g + (tid >> 6);
        int a = 0, b = n;
        while (a < b) {
            int m = (a + b) >> 1;
            if (batch[m] < key) a = m + 1;
            else b = m;
        }
        se[tid >> 6] = a;
    }
    __syncthreads();
    const int s = se[0], e = se[1];
    const int nof = tid >> 4, fq = tid & 15;
    float4 acc = make_float4(0.f, 0.f, 0.f, 0.f);
    for (int i = s + nof; i < e; i += 16) {
        size_t o = (size_t)i * 64 + fq * 4;
        float4 m4 = *(const float4*)(mean + o);
        float4 l4 = *(const float4*)(logv + o);
        float4 e4 = *(const float4*)(eps + o);
        acc.x += m4.x + e4.x * expf(0.5f * l4.x);
        acc.y += m4.y + e4.y * expf(0.5f * l4.y);
        acc.z += m4.z + e4.z * expf(0.5f * l4.z);
        acc.w += m4.w + e4.w * expf(0.5f * l4.w);
    }
    red[tid] = acc;
    __syncthreads();
    if (tid < 16) {
        float4 sum = red[fq];
        for (int j = 1; j < 16; ++j) {
            float4 r = red[j * 16 + fq];
            sum.x += r.x;
            sum.y += r.y;
            sum.z += r.z;
            sum.w += r.w;
        }
        float inv = 1.0f / (float)max(e - s, 1);
        pooled[fq * 4 + 0] = sum.x * inv;
        pooled[fq * 4 + 1] = sum.y * inv;
        pooled[fq * 4 + 2] = sum.z * inv;
        pooled[fq * 4 + 3] = sum.w * inv;
    }
    __syncthreads();
    if (tid < 128) {
        float a = fc1b[tid];
        for (int k = 0; k < 64; ++k) a = fmaf(pooled[k], fc1W[k * 128 + tid], a);
        hbuf[tid] = fmaxf(a, 0.f);
    }
    __syncthreads();
    if (tid < 2) {
        float a = fc2b[tid];
        for (int k = 0; k < 128; ++k) a = fmaf(hbuf[k], fc2W[k * 2 + tid], a);
        lg[tid] = a;
    }
    __syncthreads();
    if (tid < 2) {
        float m = fmaxf(lg[0], lg[1]);
        float lse = m + logf(expf(lg[0] - m) + expf(lg[1] - m));
        out[(size_t)g * 2 + tid] = lg[tid] - lse;
    }
}

extern "C" void kernel_launch(void* const* d_in, const int* in_sizes, int n_in,
                              void* d_out, int out_size, void* d_ws, size_t ws_size,
                              hipStream_t stream) {
    const int N = in_sizes[19];
    const int E = in_sizes[18] / 2;
    const int G = (out_size - 2 * N * NH) / NCLS;

    const float* x    = (const float*)d_in[0];
    const float* eps  = (const float*)d_in[1];
    const float* m0Wl = (const float*)d_in[2];
    const float* m0bl = (const float*)d_in[3];
    const float* m0Wr = (const float*)d_in[4];
    const float* mRWl = (const float*)d_in[5];
    const float* mRbl = (const float*)d_in[6];
    const float* mRWr = (const float*)d_in[7];
    const float* v0Wl = (const float*)d_in[8];
    const float* v0bl = (const float*)d_in[9];
    const float* v0Wr = (const float*)d_in[10];
    const float* vRWl = (const float*)d_in[11];
    const float* vRbl = (const float*)d_in[12];
    const float* vRWr = (const float*)d_in[13];
    const float* fc1W = (const float*)d_in[14];
    const float* fc1b = (const float*)d_in[15];
    const float* fc2W = (const float*)d_in[16];
    const float* fc2b = (const float*)d_in[17];
    const int* eidx   = (const int*)d_in[18];
    const int* batch  = (const int*)d_in[19];
    const int* srcI = eidx;
    const int* dstI = eidx + E;

    float* out_ls = (float*)d_out;
    float* out_mean = out_ls + (size_t)G * NCLS;
    float* out_lv = out_mean + (size_t)N * NH;
    // split-bf16 inter-layer state lives in the (not yet final) d_out region
    unsigned short* Sh_m = (unsigned short*)out_mean;
    unsigned short* Sl_m = Sh_m + (size_t)N * NH;
    unsigned short* Sh_v = (unsigned short*)out_lv;
    unsigned short* Sl_v = Sh_v + (size_t)N * NH;

    char* w = (char*)d_ws;
    auto alloc = [&](size_t bytes) {
        char* p = w;
        w += (bytes + 255) & ~(size_t)255;
        return p;
    };
    int* deg = (int*)alloc((size_t)N * 4);
    int* rowptr = (int*)alloc((size_t)(N + 1) * 4);
    int* cursor = (int*)alloc((size_t)N * 4);
    int* bsum = (int*)alloc(256 * 4);
    int* boff = (int*)alloc(256 * 4);
    int* col = (int*)alloc((size_t)E * 4);
    unsigned* TLRu = (unsigned*)alloc((size_t)N * 128 * 4);  // packed mean|var
    unsigned short* w0h = (unsigned short*)alloc(2 * 128 * 128 * 2);
    unsigned short* w0l = (unsigned short*)alloc(2 * 128 * 128 * 2);
    unsigned short* wlh = (unsigned short*)alloc(4 * 128 * 64 * 2);
    unsigned short* wll = (unsigned short*)alloc(4 * 128 * 64 * 2);
    float* biasAll = (float*)alloc(6 * 128 * 4);
    (void)ws_size;
    (void)n_in;

    const int nbE = (E + 255) / 256;
    const int nbScan = (N + 1023) / 1024;

    // CSR build (graph reused by all 3 layers)
    hipMemsetAsync(deg, 0, (size_t)N * 4, stream);
    count_deg4<<<(E + 1023) / 1024, 256, 0, stream>>>(dstI, deg, E);
    scan1<<<nbScan, 256, 0, stream>>>(deg, rowptr, bsum, N);
    scan2<<<1, 256, 0, stream>>>(bsum, boff, nbScan);
    scan3<<<(N + 256) / 256 + 1, 256, 0, stream>>>(rowptr, boff, N, E);
    hipMemsetAsync(cursor, 0, (size_t)N * 4, stream);
    for (int p = 0; p < 4; ++p) {
        int lo = (int)((long long)p * N / 4);
        int hi = (int)((long long)(p + 1) * N / 4);
        fill_csr_pass<<<nbE, 256, 0, stream>>>(srcI, dstI, rowptr, cursor, col, E, lo, hi);
    }

    // weight prep
    prep_w<<<64, 256, 0, stream>>>(m0Wl, m0Wr, m0bl, 128, w0h, w0l, biasAll);
    prep_w<<<64, 256, 0, stream>>>(v0Wl, v0Wr, v0bl, 128, w0h + 128 * 128, w0l + 128 * 128,
                                   biasAll + 128);
    for (int i = 0; i < 2; ++i) {
        prep_w<<<32, 256, 0, stream>>>(mRWl + (size_t)i * 4096, mRWr + (size_t)i * 4096,
                                       mRbl + (size_t)i * 64, 64,
                                       wlh + (size_t)(2 * i) * 8192, wll + (size_t)(2 * i) * 8192,
                                       biasAll + (2 + 2 * i) * 128);
        prep_w<<<32, 256, 0, stream>>>(vRWl + (size_t)i * 4096, vRWr + (size_t)i * 4096,
                                       vRbl + (size_t)i * 64, 64,
                                       wlh + (size_t)(2 * i + 1) * 8192,
                                       wll + (size_t)(2 * i + 1) * 8192,
                                       biasAll + (2 + 2 * i + 1) * 128);
    }

    const int nbR = (N + 63) / 64;
    const int nbAgg = (N + 15) / 16;

    // layer 0 (K=128, fp32 source, both paths in one kernel)
    gemm_dual<1><<<nbR, 256, 0, stream>>>(x, nullptr, nullptr, nullptr, nullptr,
                                          w0h, w0l, biasAll, TLRu, 128, N);
    agg_fused<0><<<nbAgg, 256, 0, stream>>>(TLRu, rowptr, col, nullptr, nullptr,
                                            Sh_m, Sl_m, Sh_v, Sl_v, N);

    // layers 1..2 (K=64, split-bf16 state)
    for (int i = 0; i < 2; ++i) {
        const bool fin = (i == 1);
        gemm_dual<0><<<nbR, 256, 0, stream>>>(nullptr, Sh_m, Sl_m, Sh_v, Sl_v,
                                              wlh + (size_t)(2 * i) * 8192,
                                              wll + (size_t)(2 * i) * 8192,
                                              biasAll + (2 + 2 * i) * 128, TLRu, 64, N);
        if (fin)
            agg_fused<1><<<nbAgg, 256, 0, stream>>>(TLRu, rowptr, col, out_mean, out_lv,
                                                    nullptr, nullptr, nullptr, nullptr, N);
        else
            agg_fused<0><<<nbAgg, 256, 0, stream>>>(TLRu, rowptr, col, nullptr, nullptr,
                                                    Sh_m, Sl_m, Sh_v, Sl_v, N);
    }

    // reparam + pool + FC head, one block per graph
    pool_head<<<G, 256, 0, stream>>>(out_mean, out_lv, eps, batch, fc1W, fc1b, fc2W, fc2b,
                                     out_ls, N);
}

// Round 7
// 518.396 us; speedup vs baseline: 3.1190x; 1.0415x over previous
//
#include <hip/hip_runtime.h>

#define NH 64
#define NCLS 2

typedef short short8 __attribute__((ext_vector_type(8)));
typedef float f32x4 __attribute__((ext_vector_type(4)));

__device__ inline unsigned short f2bf(float x) {
    unsigned u = __float_as_uint(x);
    unsigned r = (u + 0x7FFFu + ((u >> 16) & 1u)) >> 16;
    return (unsigned short)r;
}
__device__ inline float bf2f(unsigned short h) { return __uint_as_float(((unsigned)h) << 16); }
__device__ inline float bf2f_u(unsigned h) { return __uint_as_float(h << 16); }

__device__ inline void acc_u4(uint4 u, float4& am, float4& av) {
    am.x += __uint_as_float(u.x << 16);
    av.x += __uint_as_float(u.x & 0xffff0000u);
    am.y += __uint_as_float(u.y << 16);
    av.y += __uint_as_float(u.y & 0xffff0000u);
    am.z += __uint_as_float(u.z << 16);
    av.z += __uint_as_float(u.z & 0xffff0000u);
    am.w += __uint_as_float(u.w << 16);
    av.w += __uint_as_float(u.w & 0xffff0000u);
}

// ---------------- CSR build ----------------

__global__ void count_deg4(const int* __restrict__ dst, int* __restrict__ deg, int e) {
    int base = (blockIdx.x * 256 + threadIdx.x) * 4;
    if (base + 3 < e) {
        int4 d = *(const int4*)(dst + base);
        atomicAdd(&deg[d.x], 1);
        atomicAdd(&deg[d.y], 1);
        atomicAdd(&deg[d.z], 1);
        atomicAdd(&deg[d.w], 1);
    } else {
        for (int i = base; i < e; ++i) atomicAdd(&deg[dst[i]], 1);
    }
}

__global__ void scan1(const int* __restrict__ in, int* __restrict__ out,
                      int* __restrict__ bsum, int n) {
    __shared__ int s[256];
    int tid = threadIdx.x;
    int base = blockIdx.x * 1024 + tid * 4;
    int v0 = (base + 0 < n) ? in[base + 0] : 0;
    int v1 = (base + 1 < n) ? in[base + 1] : 0;
    int v2 = (base + 2 < n) ? in[base + 2] : 0;
    int v3 = (base + 3 < n) ? in[base + 3] : 0;
    int lsum = v0 + v1 + v2 + v3;
    s[tid] = lsum;
    __syncthreads();
    for (int off = 1; off < 256; off <<= 1) {
        int t = (tid >= off) ? s[tid - off] : 0;
        __syncthreads();
        s[tid] += t;
        __syncthreads();
    }
    int excl = s[tid] - lsum;
    if (base + 0 < n) out[base + 0] = excl;
    if (base + 1 < n) out[base + 1] = excl + v0;
    if (base + 2 < n) out[base + 2] = excl + v0 + v1;
    if (base + 3 < n) out[base + 3] = excl + v0 + v1 + v2;
    if (tid == 255) bsum[blockIdx.x] = s[255];
}

__global__ void scan2(const int* __restrict__ bsum, int* __restrict__ boff, int nb) {
    __shared__ int s[256];
    int tid = threadIdx.x;
    int v = (tid < nb) ? bsum[tid] : 0;
    s[tid] = v;
    __syncthreads();
    for (int off = 1; off < 256; off <<= 1) {
        int t = (tid >= off) ? s[tid - off] : 0;
        __syncthreads();
        s[tid] += t;
        __syncthreads();
    }
    if (tid < nb) boff[tid] = s[tid] - v;
}

__global__ void scan3(int* __restrict__ rowptr, const int* __restrict__ boff,
                      int n, int total) {
    int i = blockIdx.x * 256 + threadIdx.x;
    if (i < n) rowptr[i] += boff[i >> 10];
    else if (i == n) rowptr[n] = total;
}

// range-partitioned fill: only edges with dst in [lo,hi) -> write window stays in L2
__global__ void fill_csr_pass(const int* __restrict__ src, const int* __restrict__ dst,
                              const int* __restrict__ rowptr, int* __restrict__ cursor,
                              int* __restrict__ col, int e, int lo, int hi) {
    int i = blockIdx.x * 256 + threadIdx.x;
    if (i < e) {
        int d = dst[i];
        if (d >= lo && d < hi) {
            int p = atomicAdd(&cursor[d], 1);
            col[rowptr[d] + p] = src[i];
        }
    }
}

// ---------------- weight prep: W^T split bf16, cols = [TL(64) | TR(64)] ----------------

__global__ void prep_w(const float* __restrict__ Wl, const float* __restrict__ Wr,
                       const float* __restrict__ bl, int K,
                       unsigned short* __restrict__ Wth, unsigned short* __restrict__ Wtl,
                       float* __restrict__ biasOut) {
    int tot = 128 * K;
    for (int idx = blockIdx.x * 256 + threadIdx.x; idx < tot; idx += gridDim.x * 256) {
        int c = idx / K, k = idx - c * K;
        float wv = (c < 64) ? Wl[(size_t)k * 64 + c] : Wr[(size_t)k * 64 + (c - 64)];
        unsigned short h = f2bf(wv);
        Wth[idx] = h;
        Wtl[idx] = f2bf(wv - bf2f(h));
    }
    if (blockIdx.x == 0 && threadIdx.x < 128)
        biasOut[threadIdx.x] = (threadIdx.x < 64) ? 0.f : bl[threadIdx.x - 64];
}

// ---------------- dual-path split-bf16 MFMA GEMM, fp32 A from global ----------------
// A is fp32 (split to bf16 hi/lo in-register). Path 0 reads Am, path 1 reads Av
// (layer 0 passes Am==Av==x). Output TLRu[r*128+c] = bf16(mean) | bf16(var)<<16.

__launch_bounds__(256)
__global__ void gemm_dual(const float* __restrict__ Am, const float* __restrict__ Av,
                          const unsigned short* __restrict__ Wh,  // [2][128*Kg]
                          const unsigned short* __restrict__ Wl,  // [2][128*Kg]
                          const float* __restrict__ bias,         // [2][128]
                          unsigned* __restrict__ TLRu, int Kg, int Nn) {
    __shared__ unsigned short Bh[128 * 72], Bl[128 * 72];
    const int tid = threadIdx.x;
    const int l = tid & 63, w = tid >> 6;
    const int rowbase = blockIdx.x * 64;
    const int r = rowbase + w * 16 + (l & 15);
    const bool rok = r < Nn;
    const int kofs = (l >> 4) * 8;
    f32x4 acc[2][8] = {};

    bool first = true;
    for (int k0 = 0; k0 < Kg; k0 += 64) {
#pragma unroll
        for (int p = 0; p < 2; ++p) {
            if (!first) __syncthreads();
            first = false;
            // stage B (one path) into LDS
#pragma unroll
            for (int q = 0; q < 4; ++q) {
                int lin = q * 256 + tid;
                int c = lin >> 3;
                int k8 = (lin & 7) << 3;
                *(short8*)&Bh[c * 72 + k8] =
                    *(const short8*)(Wh + (size_t)p * 128 * Kg + (size_t)c * Kg + k0 + k8);
                *(short8*)&Bl[c * 72 + k8] =
                    *(const short8*)(Wl + (size_t)p * 128 * Kg + (size_t)c * Kg + k0 + k8);
            }
            __syncthreads();
            const float* As = p ? Av : Am;
#pragma unroll
            for (int kk = 0; kk < 64; kk += 32) {
                short8 a_h = {}, a_l = {};
                if (rok) {
                    const float* xr = As + (size_t)r * Kg + k0 + kofs + kk;
                    float4 v0 = *(const float4*)xr;
                    float4 v1 = *(const float4*)(xr + 4);
                    float f[8] = {v0.x, v0.y, v0.z, v0.w, v1.x, v1.y, v1.z, v1.w};
#pragma unroll
                    for (int i = 0; i < 8; ++i) {
                        unsigned short h = f2bf(f[i]);
                        a_h[i] = (short)h;
                        a_l[i] = (short)f2bf(f[i] - bf2f(h));
                    }
                }
#pragma unroll
                for (int ct = 0; ct < 8; ++ct) {
                    const int br = (ct * 16 + (l & 15)) * 72 + kk + kofs;
                    short8 b_h = *(const short8*)&Bh[br];
                    short8 b_l = *(const short8*)&Bl[br];
                    acc[p][ct] = __builtin_amdgcn_mfma_f32_16x16x32_bf16(a_h, b_h, acc[p][ct], 0, 0, 0);
                    acc[p][ct] = __builtin_amdgcn_mfma_f32_16x16x32_bf16(a_h, b_l, acc[p][ct], 0, 0, 0);
                    acc[p][ct] = __builtin_amdgcn_mfma_f32_16x16x32_bf16(a_l, b_h, acc[p][ct], 0, 0, 0);
                }
            }
        }
    }
    const int r0 = rowbase + w * 16 + ((l >> 4) << 2);
#pragma unroll
    for (int ct = 0; ct < 8; ++ct) {
        int c = ct * 16 + (l & 15);
        float b0 = bias[c];
        float b1 = bias[128 + c];
#pragma unroll
        for (int i = 0; i < 4; ++i) {
            int rr = r0 + i;
            if (rr < Nn) {
                unsigned hm = f2bf(acc[0][ct][i] + b0);
                unsigned hv = f2bf(acc[1][ct][i] + b1);
                TLRu[(size_t)rr * 128 + c] = hm | (hv << 16);
            }
        }
    }
}

// ---------------- fused CSR aggregate (mean+var): relu(agg(TL)/deg + TR) ----------------
// 16-lane group per node; lane sub owns uint4 #sub (features 4sub..4sub+3).
// Always writes fp32 state/output.

__launch_bounds__(256)
__global__ void agg_fused(const unsigned* __restrict__ TLRu,
                          const int* __restrict__ rowptr, const int* __restrict__ col,
                          float* __restrict__ outm, float* __restrict__ outv, int n) {
    int node = blockIdx.x * 16 + (threadIdx.x >> 4);
    if (node >= n) return;
    const int sub = threadIdx.x & 15;
    const int s = rowptr[node], e = rowptr[node + 1];
    float4 am0 = {0, 0, 0, 0}, av0 = {0, 0, 0, 0};
    float4 am1 = {0, 0, 0, 0}, av1 = {0, 0, 0, 0};
    int j = s;
    for (; j + 8 <= e; j += 8) {
        int c0 = col[j], c1 = col[j + 1], c2 = col[j + 2], c3 = col[j + 3];
        int c4 = col[j + 4], c5 = col[j + 5], c6 = col[j + 6], c7 = col[j + 7];
        uint4 u0 = ((const uint4*)(TLRu + (size_t)c0 * 128))[sub];
        uint4 u1 = ((const uint4*)(TLRu + (size_t)c1 * 128))[sub];
        uint4 u2 = ((const uint4*)(TLRu + (size_t)c2 * 128))[sub];
        uint4 u3 = ((const uint4*)(TLRu + (size_t)c3 * 128))[sub];
        uint4 u4 = ((const uint4*)(TLRu + (size_t)c4 * 128))[sub];
        uint4 u5 = ((const uint4*)(TLRu + (size_t)c5 * 128))[sub];
        uint4 u6 = ((const uint4*)(TLRu + (size_t)c6 * 128))[sub];
        uint4 u7 = ((const uint4*)(TLRu + (size_t)c7 * 128))[sub];
        acc_u4(u0, am0, av0);
        acc_u4(u1, am1, av1);
        acc_u4(u2, am0, av0);
        acc_u4(u3, am1, av1);
        acc_u4(u4, am0, av0);
        acc_u4(u5, am1, av1);
        acc_u4(u6, am0, av0);
        acc_u4(u7, am1, av1);
    }
    if (j + 4 <= e) {
        int c0 = col[j], c1 = col[j + 1], c2 = col[j + 2], c3 = col[j + 3];
        uint4 u0 = ((const uint4*)(TLRu + (size_t)c0 * 128))[sub];
        uint4 u1 = ((const uint4*)(TLRu + (size_t)c1 * 128))[sub];
        uint4 u2 = ((const uint4*)(TLRu + (size_t)c2 * 128))[sub];
        uint4 u3 = ((const uint4*)(TLRu + (size_t)c3 * 128))[sub];
        acc_u4(u0, am0, av0);
        acc_u4(u1, am1, av1);
        acc_u4(u2, am0, av0);
        acc_u4(u3, am1, av1);
        j += 4;
    }
    for (; j < e; ++j) {
        int c0 = col[j];
        uint4 u0 = ((const uint4*)(TLRu + (size_t)c0 * 128))[sub];
        acc_u4(u0, am0, av0);
    }
    am0.x += am1.x; am0.y += am1.y; am0.z += am1.z; am0.w += am1.w;
    av0.x += av1.x; av0.y += av1.y; av0.z += av1.z; av0.w += av1.w;

    float inv = 1.0f / (float)max(e - s, 1);
    uint4 t = ((const uint4*)(TLRu + (size_t)node * 128 + 64))[sub];
    float vm0 = fmaxf(fmaf(am0.x, inv, bf2f_u(t.x & 0xffff)), 0.f);
    float vv0 = fmaxf(fmaf(av0.x, inv, __uint_as_float(t.x & 0xffff0000u)), 0.f);
    float vm1 = fmaxf(fmaf(am0.y, inv, bf2f_u(t.y & 0xffff)), 0.f);
    float vv1 = fmaxf(fmaf(av0.y, inv, __uint_as_float(t.y & 0xffff0000u)), 0.f);
    float vm2 = fmaxf(fmaf(am0.z, inv, bf2f_u(t.z & 0xffff)), 0.f);
    float vv2 = fmaxf(fmaf(av0.z, inv, __uint_as_float(t.z & 0xffff0000u)), 0.f);
    float vm3 = fmaxf(fmaf(am0.w, inv, bf2f_u(t.w & 0xffff)), 0.f);
    float vv3 = fmaxf(fmaf(av0.w, inv, __uint_as_float(t.w & 0xffff0000u)), 0.f);
    size_t o = (size_t)node * 64 + sub * 4;
    *(float4*)(outm + o) = make_float4(vm0, vm1, vm2, vm3);
    *(float4*)(outv + o) = make_float4(vv0, vv1, vv2, vv3);
}

// ---------------- per-group: reparam + mean-pool + fc1 + relu + fc2 + log_softmax ----------------

__launch_bounds__(256)
__global__ void pool_head(const float* __restrict__ mean, const float* __restrict__ logv,
                          const float* __restrict__ eps, const int* __restrict__ batch,
                          const float* __restrict__ fc1W, const float* __restrict__ fc1b,
                          const float* __restrict__ fc2W, const float* __restrict__ fc2b,
                          float* __restrict__ out, int n) {
    __shared__ int se[2];
    __shared__ float4 red[256];
    __shared__ float pooled[64];
    __shared__ float hbuf[128];
    __shared__ float lg[2];
    const int g = blockIdx.x, tid = threadIdx.x;
    if (tid == 0 || tid == 64) {
        int key = g + (tid >> 6);
        int a = 0, b = n;
        while (a < b) {
            int m = (a + b) >> 1;
            if (batch[m] < key) a = m + 1;
            else b = m;
        }
        se[tid >> 6] = a;
    }
    __syncthreads();
    const int s = se[0], e = se[1];
    const int nof = tid >> 4, fq = tid & 15;
    float4 acc = make_float4(0.f, 0.f, 0.f, 0.f);
    for (int i = s + nof; i < e; i += 16) {
        size_t o = (size_t)i * 64 + fq * 4;
        float4 m4 = *(const float4*)(mean + o);
        float4 l4 = *(const float4*)(logv + o);
        float4 e4 = *(const float4*)(eps + o);
        acc.x += m4.x + e4.x * expf(0.5f * l4.x);
        acc.y += m4.y + e4.y * expf(0.5f * l4.y);
        acc.z += m4.z + e4.z * expf(0.5f * l4.z);
        acc.w += m4.w + e4.w * expf(0.5f * l4.w);
    }
    red[tid] = acc;
    __syncthreads();
    if (tid < 16) {
        float4 sum = red[fq];
        for (int j = 1; j < 16; ++j) {
            float4 r = red[j * 16 + fq];
            sum.x += r.x;
            sum.y += r.y;
            sum.z += r.z;
            sum.w += r.w;
        }
        float inv = 1.0f / (float)max(e - s, 1);
        pooled[fq * 4 + 0] = sum.x * inv;
        pooled[fq * 4 + 1] = sum.y * inv;
        pooled[fq * 4 + 2] = sum.z * inv;
        pooled[fq * 4 + 3] = sum.w * inv;
    }
    __syncthreads();
    if (tid < 128) {
        float a = fc1b[tid];
        for (int k = 0; k < 64; ++k) a = fmaf(pooled[k], fc1W[k * 128 + tid], a);
        hbuf[tid] = fmaxf(a, 0.f);
    }
    __syncthreads();
    if (tid < 2) {
        float a = fc2b[tid];
        for (int k = 0; k < 128; ++k) a = fmaf(hbuf[k], fc2W[k * 2 + tid], a);
        lg[tid] = a;
    }
    __syncthreads();
    if (tid < 2) {
        float m = fmaxf(lg[0], lg[1]);
        float lse = m + logf(expf(lg[0] - m) + expf(lg[1] - m));
        out[(size_t)g * 2 + tid] = lg[tid] - lse;
    }
}

extern "C" void kernel_launch(void* const* d_in, const int* in_sizes, int n_in,
                              void* d_out, int out_size, void* d_ws, size_t ws_size,
                              hipStream_t stream) {
    const int N = in_sizes[19];
    const int E = in_sizes[18] / 2;
    const int G = (out_size - 2 * N * NH) / NCLS;

    const float* x    = (const float*)d_in[0];
    const float* eps  = (const float*)d_in[1];
    const float* m0Wl = (const float*)d_in[2];
    const float* m0bl = (const float*)d_in[3];
    const float* m0Wr = (const float*)d_in[4];
    const float* mRWl = (const float*)d_in[5];
    const float* mRbl = (const float*)d_in[6];
    const float* mRWr = (const float*)d_in[7];
    const float* v0Wl = (const float*)d_in[8];
    const float* v0bl = (const float*)d_in[9];
    const float* v0Wr = (const float*)d_in[10];
    const float* vRWl = (const float*)d_in[11];
    const float* vRbl = (const float*)d_in[12];
    const float* vRWr = (const float*)d_in[13];
    const float* fc1W = (const float*)d_in[14];
    const float* fc1b = (const float*)d_in[15];
    const float* fc2W = (const float*)d_in[16];
    const float* fc2b = (const float*)d_in[17];
    const int* eidx   = (const int*)d_in[18];
    const int* batch  = (const int*)d_in[19];
    const int* srcI = eidx;
    const int* dstI = eidx + E;

    float* out_ls = (float*)d_out;
    float* out_mean = out_ls + (size_t)G * NCLS;
    float* out_lv = out_mean + (size_t)N * NH;

    char* w = (char*)d_ws;
    auto alloc = [&](size_t bytes) {
        char* p = w;
        w += (bytes + 255) & ~(size_t)255;
        return p;
    };
    int* deg = (int*)alloc((size_t)N * 4);
    int* rowptr = (int*)alloc((size_t)(N + 1) * 4);
    int* cursor = (int*)alloc((size_t)N * 4);
    int* bsum = (int*)alloc(256 * 4);
    int* boff = (int*)alloc(256 * 4);
    int* col = (int*)alloc((size_t)E * 4);
    unsigned* TLRu = (unsigned*)alloc((size_t)N * 128 * 4);  // packed mean|var
    unsigned short* w0h = (unsigned short*)alloc(2 * 128 * 128 * 2);
    unsigned short* w0l = (unsigned short*)alloc(2 * 128 * 128 * 2);
    unsigned short* wlh = (unsigned short*)alloc(4 * 128 * 64 * 2);
    unsigned short* wll = (unsigned short*)alloc(4 * 128 * 64 * 2);
    float* biasAll = (float*)alloc(6 * 128 * 4);
    (void)n_in;

    // fp32 inter-layer state: prefer workspace (keeps d_out as pure output);
    // fall back to the round-1-proven d_out placement if ws is too small.
    float* Sm;
    float* Sv;
    size_t used = (size_t)(w - (char*)d_ws);
    if (used + 2 * ((size_t)N * NH * 4 + 256) <= ws_size) {
        Sm = (float*)alloc((size_t)N * NH * 4);
        Sv = (float*)alloc((size_t)N * NH * 4);
    } else {
        Sm = out_mean;
        Sv = out_lv;
    }

    const int nbE = (E + 255) / 256;
    const int nbScan = (N + 1023) / 1024;

    // CSR build (graph reused by all 3 layers)
    hipMemsetAsync(deg, 0, (size_t)N * 4, stream);
    count_deg4<<<(E + 1023) / 1024, 256, 0, stream>>>(dstI, deg, E);
    scan1<<<nbScan, 256, 0, stream>>>(deg, rowptr, bsum, N);
    scan2<<<1, 256, 0, stream>>>(bsum, boff, nbScan);
    scan3<<<(N + 256) / 256 + 1, 256, 0, stream>>>(rowptr, boff, N, E);
    hipMemsetAsync(cursor, 0, (size_t)N * 4, stream);
    for (int p = 0; p < 4; ++p) {
        int lo = (int)((long long)p * N / 4);
        int hi = (int)((long long)(p + 1) * N / 4);
        fill_csr_pass<<<nbE, 256, 0, stream>>>(srcI, dstI, rowptr, cursor, col, E, lo, hi);
    }

    // weight prep
    prep_w<<<64, 256, 0, stream>>>(m0Wl, m0Wr, m0bl, 128, w0h, w0l, biasAll);
    prep_w<<<64, 256, 0, stream>>>(v0Wl, v0Wr, v0bl, 128, w0h + 128 * 128, w0l + 128 * 128,
                                   biasAll + 128);
    for (int i = 0; i < 2; ++i) {
        prep_w<<<32, 256, 0, stream>>>(mRWl + (size_t)i * 4096, mRWr + (size_t)i * 4096,
                                       mRbl + (size_t)i * 64, 64,
                                       wlh + (size_t)(2 * i) * 8192, wll + (size_t)(2 * i) * 8192,
                                       biasAll + (2 + 2 * i) * 128);
        prep_w<<<32, 256, 0, stream>>>(vRWl + (size_t)i * 4096, vRWr + (size_t)i * 4096,
                                       vRbl + (size_t)i * 64, 64,
                                       wlh + (size_t)(2 * i + 1) * 8192,
                                       wll + (size_t)(2 * i + 1) * 8192,
                                       biasAll + (2 + 2 * i + 1) * 128);
    }

    const int nbR = (N + 63) / 64;
    const int nbAgg = (N + 15) / 16;

    // layer 0 (K=128, x for both paths)
    gemm_dual<<<nbR, 256, 0, stream>>>(x, x, w0h, w0l, biasAll, TLRu, 128, N);
    agg_fused<<<nbAgg, 256, 0, stream>>>(TLRu, rowptr, col, Sm, Sv, N);

    // layers 1..2 (K=64, fp32 state)
    for (int i = 0; i < 2; ++i) {
        const bool fin = (i == 1);
        gemm_dual<<<nbR, 256, 0, stream>>>(Sm, Sv,
                                           wlh + (size_t)(2 * i) * 8192,
                                           wll + (size_t)(2 * i) * 8192,
                                           biasAll + (2 + 2 * i) * 128, TLRu, 64, N);
        if (fin)
            agg_fused<<<nbAgg, 256, 0, stream>>>(TLRu, rowptr, col, out_mean, out_lv, N);
        else
            agg_fused<<<nbAgg, 256, 0, stream>>>(TLRu, rowptr, col, Sm, Sv, N);
    }

    // reparam + pool + FC head, one block per graph
    pool_head<<<G, 256, 0, stream>>>(out_mean, out_lv, eps, batch, fc1W, fc1b, fc2W, fc2b,
                                     out_ls, N);
}

// Round 8
// 498.099 us; speedup vs baseline: 3.2461x; 1.0407x over previous
//
#include <hip/hip_runtime.h>

#define NH 64
#define NCLS 2

typedef short short8 __attribute__((ext_vector_type(8)));
typedef float f32x4 __attribute__((ext_vector_type(4)));

__device__ inline unsigned short f2bf(float x) {
    unsigned u = __float_as_uint(x);
    unsigned r = (u + 0x7FFFu + ((u >> 16) & 1u)) >> 16;
    return (unsigned short)r;
}
__device__ inline float bf2f(unsigned short h) { return __uint_as_float(((unsigned)h) << 16); }
__device__ inline float bf2f_u(unsigned h) { return __uint_as_float(h << 16); }

__device__ inline void acc_u4(uint4 u, float4& am, float4& av) {
    am.x += __uint_as_float(u.x << 16);
    av.x += __uint_as_float(u.x & 0xffff0000u);
    am.y += __uint_as_float(u.y << 16);
    av.y += __uint_as_float(u.y & 0xffff0000u);
    am.z += __uint_as_float(u.z << 16);
    av.z += __uint_as_float(u.z & 0xffff0000u);
    am.w += __uint_as_float(u.w << 16);
    av.w += __uint_as_float(u.w & 0xffff0000u);
}

// ---------------- CSR build helpers ----------------

__global__ void scan1(const int* __restrict__ in, int* __restrict__ out,
                      int* __restrict__ bsum, int n) {
    __shared__ int s[256];
    int tid = threadIdx.x;
    int base = blockIdx.x * 1024 + tid * 4;
    int v0 = (base + 0 < n) ? in[base + 0] : 0;
    int v1 = (base + 1 < n) ? in[base + 1] : 0;
    int v2 = (base + 2 < n) ? in[base + 2] : 0;
    int v3 = (base + 3 < n) ? in[base + 3] : 0;
    int lsum = v0 + v1 + v2 + v3;
    s[tid] = lsum;
    __syncthreads();
    for (int off = 1; off < 256; off <<= 1) {
        int t = (tid >= off) ? s[tid - off] : 0;
        __syncthreads();
        s[tid] += t;
        __syncthreads();
    }
    int excl = s[tid] - lsum;
    if (base + 0 < n) out[base + 0] = excl;
    if (base + 1 < n) out[base + 1] = excl + v0;
    if (base + 2 < n) out[base + 2] = excl + v0 + v1;
    if (base + 3 < n) out[base + 3] = excl + v0 + v1 + v2;
    if (tid == 255) bsum[blockIdx.x] = s[255];
}

__global__ void scan2(const int* __restrict__ bsum, int* __restrict__ boff, int nb) {
    __shared__ int s[256];
    int tid = threadIdx.x;
    int v = (tid < nb) ? bsum[tid] : 0;
    s[tid] = v;
    __syncthreads();
    for (int off = 1; off < 256; off <<= 1) {
        int t = (tid >= off) ? s[tid - off] : 0;
        __syncthreads();
        s[tid] += t;
        __syncthreads();
    }
    if (tid < nb) boff[tid] = s[tid] - v;
}

__global__ void scan3(int* __restrict__ rowptr, const int* __restrict__ boff,
                      int n, int total) {
    int i = blockIdx.x * 256 + threadIdx.x;
    if (i < n) rowptr[i] += boff[i >> 10];
    else if (i == n) rowptr[n] = total;
}

// range-partitioned fill: only edges with dst in [lo,hi) -> write window stays in L2
__global__ void fill_csr_pass(const int* __restrict__ src, const int* __restrict__ dst,
                              const int* __restrict__ rowptr, int* __restrict__ cursor,
                              int* __restrict__ col, int e, int lo, int hi) {
    int i = blockIdx.x * 256 + threadIdx.x;
    if (i < e) {
        int d = dst[i];
        if (d >= lo && d < hi) {
            int p = atomicAdd(&cursor[d], 1);
            col[rowptr[d] + p] = src[i];
        }
    }
}

// ---------------- weight prep (all 6 sets in one kernel) ----------------

__device__ void prep_one(const float* __restrict__ Wl, const float* __restrict__ Wr,
                         const float* __restrict__ bl, int K,
                         unsigned short* __restrict__ Wth, unsigned short* __restrict__ Wtl,
                         float* __restrict__ biasOut, int gid, int gsz) {
    int tot = 128 * K;
    for (int idx = gid; idx < tot; idx += gsz) {
        int c = idx / K, k = idx - c * K;
        float wv = (c < 64) ? Wl[(size_t)k * 64 + c] : Wr[(size_t)k * 64 + (c - 64)];
        unsigned short h = f2bf(wv);
        Wth[idx] = h;
        Wtl[idx] = f2bf(wv - bf2f(h));
    }
    for (int idx = gid; idx < 128; idx += gsz)
        biasOut[idx] = (idx < 64) ? 0.f : bl[idx - 64];
}

__global__ void prep_all(const float* __restrict__ m0Wl, const float* __restrict__ m0Wr,
                         const float* __restrict__ m0bl,
                         const float* __restrict__ v0Wl, const float* __restrict__ v0Wr,
                         const float* __restrict__ v0bl,
                         const float* __restrict__ mRWl, const float* __restrict__ mRWr,
                         const float* __restrict__ mRbl,
                         const float* __restrict__ vRWl, const float* __restrict__ vRWr,
                         const float* __restrict__ vRbl,
                         unsigned short* __restrict__ w0h, unsigned short* __restrict__ w0l,
                         unsigned short* __restrict__ wlh, unsigned short* __restrict__ wll,
                         float* __restrict__ biasAll) {
    int gid = blockIdx.x * 256 + threadIdx.x;
    int gsz = gridDim.x * 256;
    prep_one(m0Wl, m0Wr, m0bl, 128, w0h, w0l, biasAll, gid, gsz);
    prep_one(v0Wl, v0Wr, v0bl, 128, w0h + 128 * 128, w0l + 128 * 128, biasAll + 128, gid, gsz);
    for (int i = 0; i < 2; ++i) {
        prep_one(mRWl + (size_t)i * 4096, mRWr + (size_t)i * 4096, mRbl + (size_t)i * 64, 64,
                 wlh + (size_t)(2 * i) * 8192, wll + (size_t)(2 * i) * 8192,
                 biasAll + (2 + 2 * i) * 128, gid, gsz);
        prep_one(vRWl + (size_t)i * 4096, vRWr + (size_t)i * 4096, vRbl + (size_t)i * 64, 64,
                 wlh + (size_t)(2 * i + 1) * 8192, wll + (size_t)(2 * i + 1) * 8192,
                 biasAll + (2 + 2 * i + 1) * 128, gid, gsz);
    }
}

// ---------------- dual-path split-bf16 MFMA GEMM, fp32 A from global ----------------
// Blocks [0, nbR) do the GEMM; blocks [nbR, nbR+nbC) count degrees (layer 0 only).
// A is fp32 (split to bf16 hi/lo in-register). Path 0 reads Am, path 1 reads Av.
// Output TLRu[r*128+c] = bf16(mean) | bf16(var)<<16 ; c<64: TL, c>=64: TR(+bias).

__launch_bounds__(256)
__global__ void gemm_dual(const float* __restrict__ Am, const float* __restrict__ Av,
                          const unsigned short* __restrict__ Wh,  // [2][128*Kg]
                          const unsigned short* __restrict__ Wl,  // [2][128*Kg]
                          const float* __restrict__ bias,         // [2][128]
                          unsigned* __restrict__ TLRu, int Kg, int Nn, int nbR,
                          const int* __restrict__ dstE, int* __restrict__ deg, int E) {
    __shared__ unsigned short Bh[128 * 72], Bl[128 * 72];
    if (blockIdx.x >= nbR) {
        // degree-count role (atomic-bound; co-scheduled with the GEMM blocks)
        int base = ((blockIdx.x - nbR) * 256 + threadIdx.x) * 4;
        if (base + 3 < E) {
            int4 d = *(const int4*)(dstE + base);
            atomicAdd(&deg[d.x], 1);
            atomicAdd(&deg[d.y], 1);
            atomicAdd(&deg[d.z], 1);
            atomicAdd(&deg[d.w], 1);
        } else {
            for (int i = base; i < E; ++i) atomicAdd(&deg[dstE[i]], 1);
        }
        return;
    }
    const int tid = threadIdx.x;
    const int l = tid & 63, w = tid >> 6;
    const int rowbase = blockIdx.x * 64;
    const int r = rowbase + w * 16 + (l & 15);
    const bool rok = r < Nn;
    const int kofs = (l >> 4) * 8;
    f32x4 acc[2][8] = {};

    bool first = true;
    for (int k0 = 0; k0 < Kg; k0 += 64) {
#pragma unroll
        for (int p = 0; p < 2; ++p) {
            if (!first) __syncthreads();
            first = false;
            // stage B (one path) into LDS
#pragma unroll
            for (int q = 0; q < 4; ++q) {
                int lin = q * 256 + tid;
                int c = lin >> 3;
                int k8 = (lin & 7) << 3;
                *(short8*)&Bh[c * 72 + k8] =
                    *(const short8*)(Wh + (size_t)p * 128 * Kg + (size_t)c * Kg + k0 + k8);
                *(short8*)&Bl[c * 72 + k8] =
                    *(const short8*)(Wl + (size_t)p * 128 * Kg + (size_t)c * Kg + k0 + k8);
            }
            __syncthreads();
            const float* As = p ? Av : Am;
#pragma unroll
            for (int kk = 0; kk < 64; kk += 32) {
                short8 a_h = {}, a_l = {};
                if (rok) {
                    const float* xr = As + (size_t)r * Kg + k0 + kofs + kk;
                    float4 v0 = *(const float4*)xr;
                    float4 v1 = *(const float4*)(xr + 4);
                    float f[8] = {v0.x, v0.y, v0.z, v0.w, v1.x, v1.y, v1.z, v1.w};
#pragma unroll
                    for (int i = 0; i < 8; ++i) {
                        unsigned short h = f2bf(f[i]);
                        a_h[i] = (short)h;
                        a_l[i] = (short)f2bf(f[i] - bf2f(h));
                    }
                }
#pragma unroll
                for (int ct = 0; ct < 8; ++ct) {
                    const int br = (ct * 16 + (l & 15)) * 72 + kk + kofs;
                    short8 b_h = *(const short8*)&Bh[br];
                    short8 b_l = *(const short8*)&Bl[br];
                    acc[p][ct] = __builtin_amdgcn_mfma_f32_16x16x32_bf16(a_h, b_h, acc[p][ct], 0, 0, 0);
                    acc[p][ct] = __builtin_amdgcn_mfma_f32_16x16x32_bf16(a_h, b_l, acc[p][ct], 0, 0, 0);
                    acc[p][ct] = __builtin_amdgcn_mfma_f32_16x16x32_bf16(a_l, b_h, acc[p][ct], 0, 0, 0);
                }
            }
        }
    }
    const int r0 = rowbase + w * 16 + ((l >> 4) << 2);
#pragma unroll
    for (int ct = 0; ct < 8; ++ct) {
        int c = ct * 16 + (l & 15);
        float b0 = bias[c];
        float b1 = bias[128 + c];
#pragma unroll
        for (int i = 0; i < 4; ++i) {
            int rr = r0 + i;
            if (rr < Nn) {
                unsigned hm = f2bf(acc[0][ct][i] + b0);
                unsigned hv = f2bf(acc[1][ct][i] + b1);
                TLRu[(size_t)rr * 128 + c] = hm | (hv << 16);
            }
        }
    }
}

// ---------------- fused CSR aggregate (mean+var): relu(agg(TL)/deg + TR) ----------------
// 16-lane group per node; lane sub owns uint4 #sub (features 4sub..4sub+3).

__launch_bounds__(256)
__global__ void agg_fused(const unsigned* __restrict__ TLRu,
                          const int* __restrict__ rowptr, const int* __restrict__ col,
                          float* __restrict__ outm, float* __restrict__ outv, int n) {
    int node = blockIdx.x * 16 + (threadIdx.x >> 4);
    if (node >= n) return;
    const int sub = threadIdx.x & 15;
    const int s = rowptr[node], e = rowptr[node + 1];
    float4 am0 = {0, 0, 0, 0}, av0 = {0, 0, 0, 0};
    float4 am1 = {0, 0, 0, 0}, av1 = {0, 0, 0, 0};
    int j = s;
    for (; j + 8 <= e; j += 8) {
        int c0 = col[j], c1 = col[j + 1], c2 = col[j + 2], c3 = col[j + 3];
        int c4 = col[j + 4], c5 = col[j + 5], c6 = col[j + 6], c7 = col[j + 7];
        uint4 u0 = ((const uint4*)(TLRu + (size_t)c0 * 128))[sub];
        uint4 u1 = ((const uint4*)(TLRu + (size_t)c1 * 128))[sub];
        uint4 u2 = ((const uint4*)(TLRu + (size_t)c2 * 128))[sub];
        uint4 u3 = ((const uint4*)(TLRu + (size_t)c3 * 128))[sub];
        uint4 u4 = ((const uint4*)(TLRu + (size_t)c4 * 128))[sub];
        uint4 u5 = ((const uint4*)(TLRu + (size_t)c5 * 128))[sub];
        uint4 u6 = ((const uint4*)(TLRu + (size_t)c6 * 128))[sub];
        uint4 u7 = ((const uint4*)(TLRu + (size_t)c7 * 128))[sub];
        acc_u4(u0, am0, av0);
        acc_u4(u1, am1, av1);
        acc_u4(u2, am0, av0);
        acc_u4(u3, am1, av1);
        acc_u4(u4, am0, av0);
        acc_u4(u5, am1, av1);
        acc_u4(u6, am0, av0);
        acc_u4(u7, am1, av1);
    }
    if (j + 4 <= e) {
        int c0 = col[j], c1 = col[j + 1], c2 = col[j + 2], c3 = col[j + 3];
        uint4 u0 = ((const uint4*)(TLRu + (size_t)c0 * 128))[sub];
        uint4 u1 = ((const uint4*)(TLRu + (size_t)c1 * 128))[sub];
        uint4 u2 = ((const uint4*)(TLRu + (size_t)c2 * 128))[sub];
        uint4 u3 = ((const uint4*)(TLRu + (size_t)c3 * 128))[sub];
        acc_u4(u0, am0, av0);
        acc_u4(u1, am1, av1);
        acc_u4(u2, am0, av0);
        acc_u4(u3, am1, av1);
        j += 4;
    }
    for (; j < e; ++j) {
        int c0 = col[j];
        uint4 u0 = ((const uint4*)(TLRu + (size_t)c0 * 128))[sub];
        acc_u4(u0, am0, av0);
    }
    am0.x += am1.x; am0.y += am1.y; am0.z += am1.z; am0.w += am1.w;
    av0.x += av1.x; av0.y += av1.y; av0.z += av1.z; av0.w += av1.w;

    float inv = 1.0f / (float)max(e - s, 1);
    uint4 t = ((const uint4*)(TLRu + (size_t)node * 128 + 64))[sub];
    float vm0 = fmaxf(fmaf(am0.x, inv, bf2f_u(t.x & 0xffff)), 0.f);
    float vv0 = fmaxf(fmaf(av0.x, inv, __uint_as_float(t.x & 0xffff0000u)), 0.f);
    float vm1 = fmaxf(fmaf(am0.y, inv, bf2f_u(t.y & 0xffff)), 0.f);
    float vv1 = fmaxf(fmaf(av0.y, inv, __uint_as_float(t.y & 0xffff0000u)), 0.f);
    float vm2 = fmaxf(fmaf(am0.z, inv, bf2f_u(t.z & 0xffff)), 0.f);
    float vv2 = fmaxf(fmaf(av0.z, inv, __uint_as_float(t.z & 0xffff0000u)), 0.f);
    float vm3 = fmaxf(fmaf(am0.w, inv, bf2f_u(t.w & 0xffff)), 0.f);
    float vv3 = fmaxf(fmaf(av0.w, inv, __uint_as_float(t.w & 0xffff0000u)), 0.f);
    size_t o = (size_t)node * 64 + sub * 4;
    *(float4*)(outm + o) = make_float4(vm0, vm1, vm2, vm3);
    *(float4*)(outv + o) = make_float4(vv0, vv1, vv2, vv3);
}

// ---------------- per-group: reparam + mean-pool + fc1 + relu + fc2 + log_softmax ----------------

__launch_bounds__(256)
__global__ void pool_head(const float* __restrict__ mean, const float* __restrict__ logv,
                          const float* __restrict__ eps, const int* __restrict__ batch,
                          const float* __restrict__ fc1W, const float* __restrict__ fc1b,
                          const float* __restrict__ fc2W, const float* __restrict__ fc2b,
                          float* __restrict__ out, int n) {
    __shared__ int se[2];
    __shared__ float4 red[256];
    __shared__ float pooled[64];
    __shared__ float hbuf[128];
    __shared__ float lg[2];
    const int g = blockIdx.x, tid = threadIdx.x;
    if (tid == 0 || tid == 64) {
        int key = g + (tid >> 6);
        int a = 0, b = n;
        while (a < b) {
            int m = (a + b) >> 1;
            if (batch[m] < key) a = m + 1;
            else b = m;
        }
        se[tid >> 6] = a;
    }
    __syncthreads();
    const int s = se[0], e = se[1];
    const int nof = tid >> 4, fq = tid & 15;
    float4 acc = make_float4(0.f, 0.f, 0.f, 0.f);
    for (int i = s + nof; i < e; i += 16) {
        size_t o = (size_t)i * 64 + fq * 4;
        float4 m4 = *(const float4*)(mean + o);
        float4 l4 = *(const float4*)(logv + o);
        float4 e4 = *(const float4*)(eps + o);
        acc.x += m4.x + e4.x * expf(0.5f * l4.x);
        acc.y += m4.y + e4.y * expf(0.5f * l4.y);
        acc.z += m4.z + e4.z * expf(0.5f * l4.z);
        acc.w += m4.w + e4.w * expf(0.5f * l4.w);
    }
    red[tid] = acc;
    __syncthreads();
    if (tid < 16) {
        float4 sum = red[fq];
        for (int j = 1; j < 16; ++j) {
            float4 r = red[j * 16 + fq];
            sum.x += r.x;
            sum.y += r.y;
            sum.z += r.z;
            sum.w += r.w;
        }
        float inv = 1.0f / (float)max(e - s, 1);
        pooled[fq * 4 + 0] = sum.x * inv;
        pooled[fq * 4 + 1] = sum.y * inv;
        pooled[fq * 4 + 2] = sum.z * inv;
        pooled[fq * 4 + 3] = sum.w * inv;
    }
    __syncthreads();
    if (tid < 128) {
        float a = fc1b[tid];
        for (int k = 0; k < 64; ++k) a = fmaf(pooled[k], fc1W[k * 128 + tid], a);
        hbuf[tid] = fmaxf(a, 0.f);
    }
    __syncthreads();
    if (tid < 2) {
        float a = fc2b[tid];
        for (int k = 0; k < 128; ++k) a = fmaf(hbuf[k], fc2W[k * 2 + tid], a);
        lg[tid] = a;
    }
    __syncthreads();
    if (tid < 2) {
        float m = fmaxf(lg[0], lg[1]);
        float lse = m + logf(expf(lg[0] - m) + expf(lg[1] - m));
        out[(size_t)g * 2 + tid] = lg[tid] - lse;
    }
}

extern "C" void kernel_launch(void* const* d_in, const int* in_sizes, int n_in,
                              void* d_out, int out_size, void* d_ws, size_t ws_size,
                              hipStream_t stream) {
    const int N = in_sizes[19];
    const int E = in_sizes[18] / 2;
    const int G = (out_size - 2 * N * NH) / NCLS;

    const float* x    = (const float*)d_in[0];
    const float* eps  = (const float*)d_in[1];
    const float* m0Wl = (const float*)d_in[2];
    const float* m0bl = (const float*)d_in[3];
    const float* m0Wr = (const float*)d_in[4];
    const float* mRWl = (const float*)d_in[5];
    const float* mRbl = (const float*)d_in[6];
    const float* mRWr = (const float*)d_in[7];
    const float* v0Wl = (const float*)d_in[8];
    const float* v0bl = (const float*)d_in[9];
    const float* v0Wr = (const float*)d_in[10];
    const float* vRWl = (const float*)d_in[11];
    const float* vRbl = (const float*)d_in[12];
    const float* vRWr = (const float*)d_in[13];
    const float* fc1W = (const float*)d_in[14];
    const float* fc1b = (const float*)d_in[15];
    const float* fc2W = (const float*)d_in[16];
    const float* fc2b = (const float*)d_in[17];
    const int* eidx   = (const int*)d_in[18];
    const int* batch  = (const int*)d_in[19];
    const int* srcI = eidx;
    const int* dstI = eidx + E;

    float* out_ls = (float*)d_out;
    float* out_mean = out_ls + (size_t)G * NCLS;
    float* out_lv = out_mean + (size_t)N * NH;

    char* w = (char*)d_ws;
    auto alloc = [&](size_t bytes) {
        char* p = w;
        w += (bytes + 255) & ~(size_t)255;
        return p;
    };
    int* degcur = (int*)alloc((size_t)2 * N * 4);  // deg | cursor, one memset
    int* deg = degcur;
    int* cursor = degcur + N;
    int* rowptr = (int*)alloc((size_t)(N + 1) * 4);
    int* bsum = (int*)alloc(256 * 4);
    int* boff = (int*)alloc(256 * 4);
    int* col = (int*)alloc((size_t)E * 4);
    unsigned* TLRu = (unsigned*)alloc((size_t)N * 128 * 4);  // packed mean|var
    unsigned short* w0h = (unsigned short*)alloc(2 * 128 * 128 * 2);
    unsigned short* w0l = (unsigned short*)alloc(2 * 128 * 128 * 2);
    unsigned short* wlh = (unsigned short*)alloc(4 * 128 * 64 * 2);
    unsigned short* wll = (unsigned short*)alloc(4 * 128 * 64 * 2);
    float* biasAll = (float*)alloc(6 * 128 * 4);
    (void)n_in;

    // fp32 inter-layer state: prefer workspace; fall back to d_out placement.
    float* Sm;
    float* Sv;
    size_t used = (size_t)(w - (char*)d_ws);
    if (used + 2 * ((size_t)N * NH * 4 + 256) <= ws_size) {
        Sm = (float*)alloc((size_t)N * NH * 4);
        Sv = (float*)alloc((size_t)N * NH * 4);
    } else {
        Sm = out_mean;
        Sv = out_lv;
    }

    const int nbE = (E + 255) / 256;
    const int nbScan = (N + 1023) / 1024;
    const int nbR = (N + 63) / 64;
    const int nbC = (E + 1023) / 1024;
    const int nbAgg = (N + 15) / 16;

    hipMemsetAsync(degcur, 0, (size_t)2 * N * 4, stream);

    // weight prep (gemm layer-0 needs w0h/w0l first)
    prep_all<<<128, 256, 0, stream>>>(m0Wl, m0Wr, m0bl, v0Wl, v0Wr, v0bl,
                                      mRWl, mRWr, mRbl, vRWl, vRWr, vRbl,
                                      w0h, w0l, wlh, wll, biasAll);

    // D1: layer-0 GEMM (blocks < nbR) + degree count (blocks >= nbR), co-scheduled
    gemm_dual<<<nbR + nbC, 256, 0, stream>>>(x, x, w0h, w0l, biasAll, TLRu, 128, N,
                                             nbR, dstI, deg, E);

    // rowptr = exclusive scan(deg)
    scan1<<<nbScan, 256, 0, stream>>>(deg, rowptr, bsum, N);
    scan2<<<1, 256, 0, stream>>>(bsum, boff, nbScan);
    scan3<<<(N + 256) / 256 + 1, 256, 0, stream>>>(rowptr, boff, N, E);
    for (int p = 0; p < 4; ++p) {
        int lo = (int)((long long)p * N / 4);
        int hi = (int)((long long)(p + 1) * N / 4);
        fill_csr_pass<<<nbE, 256, 0, stream>>>(srcI, dstI, rowptr, cursor, col, E, lo, hi);
    }

    // layer 0 aggregate
    agg_fused<<<nbAgg, 256, 0, stream>>>(TLRu, rowptr, col, Sm, Sv, N);

    // layers 1..2 (K=64, fp32 state)
    for (int i = 0; i < 2; ++i) {
        const bool fin = (i == 1);
        gemm_dual<<<nbR, 256, 0, stream>>>(Sm, Sv,
                                           wlh + (size_t)(2 * i) * 8192,
                                           wll + (size_t)(2 * i) * 8192,
                                           biasAll + (2 + 2 * i) * 128, TLRu, 64, N,
                                           nbR, nullptr, nullptr, 0);
        if (fin)
            agg_fused<<<nbAgg, 256, 0, stream>>>(TLRu, rowptr, col, out_mean, out_lv, N);
        else
            agg_fused<<<nbAgg, 256, 0, stream>>>(TLRu, rowptr, col, Sm, Sv, N);
    }

    // reparam + pool + FC head, one block per graph
    pool_head<<<G, 256, 0, stream>>>(out_mean, out_lv, eps, batch, fc1W, fc1b, fc2W, fc2b,
                                     out_ls, N);
}